// Round 11
// baseline (2287.400 us; speedup 1.0000x reference)
//
#include <hip/hip_runtime.h>
#include <math.h>

// Sizes: B=8, IN=2, N=512, T_IN=13, RC=DC=32, SC=256, EC=512, EMB=16, DATT=16, L=8

typedef short v4s __attribute__((ext_vector_type(4)));
typedef float v4f __attribute__((ext_vector_type(4)));
typedef unsigned short ushort_t;

#define MFMA16(a,b,c) __builtin_amdgcn_mfma_f32_16x16x16bf16_1k(a, b, c, 0, 0, 0)

__device__ inline ushort_t f2bf(float f){
    unsigned int u = __builtin_bit_cast(unsigned int, f);
    u += 0x7FFFu + ((u >> 16) & 1u);
    return (ushort_t)(u >> 16);
}
__device__ inline float bf2f(ushort_t h){
    return __builtin_bit_cast(float, ((unsigned int)h) << 16);
}

struct MegaParams {
    const float *inp, *start_w, *start_b, *gat;
    const float *q_w, *q_b, *k_w, *k_b;
    const float *filt_w, *filt_b, *gate_w, *gate_b;
    const float *skip_w, *skip_b;
    const float *gmlp_w, *gmlp_b;
    const float *bn_g, *bn_b;
    const float *w1, *b1, *w2, *b2;
    float *out;
    float *skip, *bnsum, *bufA, *bufB, *qe, *ke, *rz;
    ushort_t *xbfT, *qbf, *kbf;
    ushort_t *cwh, *cwl, *qkw, *swh, *swl, *w1ph, *w1pl, *w2ph, *w2pl;
    unsigned *bcnt, *bgen;
};

// Device-scope grid barrier. Safe because grid <= co-resident capacity (2 blocks/CU by LDS).
__device__ inline void gbar(unsigned* cnt, unsigned* gen, int nb){
    __syncthreads();
    __threadfence();   // release: publish this block's global writes (L2 writeback, agent scope)
    if (threadIdx.x == 0){
        unsigned g = __hip_atomic_load(gen, __ATOMIC_RELAXED, __HIP_MEMORY_SCOPE_AGENT);
        unsigned old = __hip_atomic_fetch_add(cnt, 1u, __ATOMIC_ACQ_REL, __HIP_MEMORY_SCOPE_AGENT);
        if (old == (unsigned)(nb - 1)){
            __hip_atomic_store(cnt, 0u, __ATOMIC_RELAXED, __HIP_MEMORY_SCOPE_AGENT);
            __hip_atomic_fetch_add(gen, 1u, __ATOMIC_RELEASE, __HIP_MEMORY_SCOPE_AGENT);
        } else {
            while (__hip_atomic_load(gen, __ATOMIC_ACQUIRE, __HIP_MEMORY_SCOPE_AGENT) == g)
                __builtin_amdgcn_s_sleep(2);
        }
    }
    __syncthreads();
    __threadfence();   // acquire: invalidate stale lines before reading others' writes
}

__global__ void __launch_bounds__(256) k_mega(MegaParams p)
{
    __shared__ __align__(16) char LB[58368];
    int tid = threadIdx.x;
    int bid = blockIdx.x, nb = gridDim.x;
    int lane = tid & 63, wid = tid >> 6;
    int m16 = lane & 15, g4 = (lane >> 4)*4;

    // ================= PREP =================
    for (int blk = bid; blk < 12226; blk += nb){
        int idx = blk*256 + tid;
        const int E0 = 1049024;
        const int E1 = E0 + 131072;
        const int E2 = E1 + 1703936;
        const int E3 = E2 + 32768;
        const int E4 = E3 + 8192;
        const int E5 = E4 + 65536;
        const int E6 = E5 + 131072;
        const int E7 = E6 + 8192;
        if (idx < E0){
            p.skip[idx] = 0.0f;   // covers skip (1048576) + bnsum (448), contiguous
        } else if (idx < E1){
            int id = idx - E0;
            const int total = 8*512*16;
            bool isK = id >= total;
            if (isK) id -= total;
            int dq = id & 15; int n = (id >> 4) & 511; int l = id >> 13;
            const float* w = isK ? p.k_w : p.q_w;
            const float* bi = isK ? p.k_b : p.q_b;
            float acc = bi[l*16 + dq];
            const float* wrow = w + (l*16 + dq)*48 + 32;
            #pragma unroll
            for (int e = 0; e < 16; e++) acc += wrow[e] * p.gat[e*512 + n];
            (isK ? p.ke : p.qe)[(l*512 + n)*16 + dq] = isK ? acc : acc*0.25f;
        } else if (idx < E2){
            int id = idx - E1;
            int n = id & 511; int c = (id >> 9) & 31; int r = id >> 14;
            int t = r % 13; int b = r / 13;
            float v0 = p.inp[((b*2 + 0)*512 + n)*13 + t];
            float v1 = p.inp[((b*2 + 1)*512 + n)*13 + t];
            p.bufA[id] = p.start_b[c] + p.start_w[c*2 + 0]*v0 + p.start_w[c*2 + 1]*v1;
        } else if (idx < E3){
            int id = idx - E2;
            int k = id & 63, o = (id >> 6) & 63, l = id >> 12;
            int c = k & 31, tap = k >> 5;
            float w = (o < 32) ? p.filt_w[((l*32 + o)*32 + c)*2 + tap]
                               : p.gate_w[((l*32 + (o-32))*32 + c)*2 + tap];
            ushort_t hi = f2bf(w);
            p.cwh[id] = hi; p.cwl[id] = f2bf(w - bf2f(hi));
        } else if (idx < E4){
            int id = idx - E3;
            int c = id & 31, j = (id >> 5) & 31, l = id >> 10;
            float w = (j < 16) ? p.q_w[(l*16 + j)*48 + c]*0.25f : p.k_w[(l*16 + (j-16))*48 + c];
            p.qkw[id] = f2bf(w);
        } else if (idx < E5){
            int id = idx - E4;
            float w = p.skip_w[id];
            ushort_t hi = f2bf(w);
            p.swh[id] = hi; p.swl[id] = f2bf(w - bf2f(hi));
        } else if (idx < E6){
            int id = idx - E5;
            int j = id & 15, mm = (id >> 4) & 15, kk = (id >> 8) & 15, ot = id >> 12;
            float w = p.w1[((size_t)(ot*16 + mm))*256 + kk*16 + j];
            ushort_t hi = f2bf(w);
            p.w1ph[id] = hi; p.w1pl[id] = f2bf(w - bf2f(hi));
        } else if (idx < E7){
            int id = idx - E6;
            int j = id & 15, mm = (id >> 4) & 15, kt = id >> 8;
            float w = (mm < 12) ? p.w2[mm*512 + kt*16 + j] : 0.0f;
            ushort_t hi = f2bf(w);
            p.w2ph[id] = hi; p.w2pl[id] = f2bf(w - bf2f(hi));
        }
    }
    gbar(p.bcnt, p.bgen, nb);

    const int TinA[8] = {13,12,10,9,7,6,4,3};
    const int DdA[8]  = {1,2,1,2,1,2,1,2};
    float* xin = p.bufA; float* yb = p.bufB;

    for (int L = 0; L < 8; L++){
        int Ti = TinA[L], d = DdA[L], To = Ti - d;
        const float* bnsumP = (L == 0) ? p.bnsum : p.bnsum + (L-1)*64;
        const float* gP = (L == 0) ? p.bn_g : p.bn_g + (L-1)*32;
        const float* bP = (L == 0) ? p.bn_b : p.bn_b + (L-1)*32;
        float cnt = 8.0f * (float)Ti * 512.0f;
        const ushort_t* cwhL = p.cwh + L*4096;
        const ushort_t* cwlL = p.cwl + L*4096;
        const ushort_t* qkwL = p.qkw + L*1024;
        const float* qeL = p.qe + L*8192;
        const float* keL = p.ke + L*8192;
        const ushort_t* swhL = p.swh + L*8192;
        const ushort_t* swlL = p.swl + L*8192;
        const float* sbL = p.skip_b + L*256;
        const float* fbL = p.filt_b + L*32;
        const float* gbL = p.gate_b + L*32;
        int do_qk = (L < 7);

        // ========== PHASE A: gated conv + q/k + skip ==========
        int nA = 4*To*8;
        for (int it = bid; it < nA; it += nb){
            int nch = it & 3; int r = it >> 2; int t = r % To; int b = r / To;
            unsigned int* XBP = (unsigned int*)LB;          // 64*129
            float* ABsh = (float*)(LB + 33024);             // 64
            size_t bt = (size_t)(b*To + t);
            int n0 = nch*128;
            if (tid < 32){
                float A, Bc;
                if (L == 0){ A = 1.0f; Bc = 0.0f; }
                else {
                    float S = bnsumP[2*tid], S2 = bnsumP[2*tid + 1];
                    float m = S/cnt, var = S2/cnt - m*m;
                    A = gP[tid]*rsqrtf(var + 1e-5f);
                    Bc = bP[tid] - m*A;
                }
                ABsh[tid] = A; ABsh[32 + tid] = Bc;
            }
            __syncthreads();
            #pragma unroll
            for (int kk = 0; kk < 16; kk++){
                int k = wid*16 + kk;
                int c = k & 31, tap = k >> 5;
                const float* src = xin + ((size_t)(b*Ti + t + tap*d)*32 + c)*512 + n0 + lane;
                float An = ABsh[c], Bn = ABsh[32 + c];
                #pragma unroll
                for (int h = 0; h < 2; h++){
                    float xn = An*src[h*64] + Bn;
                    ushort_t hi = f2bf(xn);
                    ushort_t lo = f2bf(xn - bf2f(hi));
                    XBP[k*129 + h*64 + lane] = (unsigned int)hi | ((unsigned int)lo << 16);
                }
            }
            v4s ah[4][4], al[4][4];
            #pragma unroll
            for (int ot = 0; ot < 4; ot++)
            #pragma unroll
            for (int kt = 0; kt < 4; kt++){
                ah[ot][kt] = *(const v4s*)(cwhL + (ot*16 + m16)*64 + kt*16 + g4);
                al[ot][kt] = *(const v4s*)(cwlL + (ot*16 + m16)*64 + kt*16 + g4);
            }
            v4f acc[4][2];
            #pragma unroll
            for (int ot = 0; ot < 4; ot++){
                float4 bv = *(const float4*)((ot < 2 ? fbL + ot*16 : gbL + (ot-2)*16) + g4);
                acc[ot][0] = (v4f){bv.x, bv.y, bv.z, bv.w};
                acc[ot][1] = (v4f){bv.x, bv.y, bv.z, bv.w};
            }
            __syncthreads();
            v4s bh[2][4], bl[2][4];
            #pragma unroll
            for (int nt = 0; nt < 2; nt++){
                int nl = (wid*2 + nt)*16 + m16;
                #pragma unroll
                for (int kt = 0; kt < 4; kt++){
                    unsigned int u0 = XBP[(kt*16 + g4 + 0)*129 + nl];
                    unsigned int u1 = XBP[(kt*16 + g4 + 1)*129 + nl];
                    unsigned int u2 = XBP[(kt*16 + g4 + 2)*129 + nl];
                    unsigned int u3 = XBP[(kt*16 + g4 + 3)*129 + nl];
                    v4s hh, ll;
                    hh[0] = (short)(u0 & 0xffffu); ll[0] = (short)(u0 >> 16);
                    hh[1] = (short)(u1 & 0xffffu); ll[1] = (short)(u1 >> 16);
                    hh[2] = (short)(u2 & 0xffffu); ll[2] = (short)(u2 >> 16);
                    hh[3] = (short)(u3 & 0xffffu); ll[3] = (short)(u3 >> 16);
                    bh[nt][kt] = hh; bl[nt][kt] = ll;
                }
            }
            #pragma unroll
            for (int kt = 0; kt < 4; kt++)
            #pragma unroll
            for (int ot = 0; ot < 4; ot++)
            #pragma unroll
            for (int nt = 0; nt < 2; nt++){
                acc[ot][nt] = MFMA16(ah[ot][kt], bh[nt][kt], acc[ot][nt]);
                acc[ot][nt] = MFMA16(ah[ot][kt], bl[nt][kt], acc[ot][nt]);
                acc[ot][nt] = MFMA16(al[ot][kt], bh[nt][kt], acc[ot][nt]);
            }
            v4s xh[2][2], xl[2][2];
            #pragma unroll
            for (int ct = 0; ct < 2; ct++)
            #pragma unroll
            for (int nt = 0; nt < 2; nt++){
                v4s hh, ll;
                #pragma unroll
                for (int i = 0; i < 4; i++){
                    float f = acc[ct][nt][i], g = acc[ct+2][nt][i];
                    float e2 = __expf(2.0f*f);
                    float th = 1.0f - 2.0f/(e2 + 1.0f);
                    float sg = 1.0f/(1.0f + __expf(-g));
                    float v = th*sg;
                    ushort_t hi = f2bf(v);
                    hh[i] = (short)hi; ll[i] = (short)f2bf(v - bf2f(hi));
                }
                xh[ct][nt] = hh; xl[ct][nt] = ll;
            }
            if (do_qk){
                #pragma unroll
                for (int ct = 0; ct < 2; ct++)
                #pragma unroll
                for (int nt = 0; nt < 2; nt++){
                    int nl = n0 + (wid*2 + nt)*16 + m16;
                    #pragma unroll
                    for (int i = 0; i < 4; i++)
                        p.xbfT[(bt*32 + ct*16 + g4 + i)*512 + nl] = (ushort_t)xh[ct][nt][i];
                }
                v4s qa[2][2];
                #pragma unroll
                for (int ot = 0; ot < 2; ot++)
                #pragma unroll
                for (int kt = 0; kt < 2; kt++)
                    qa[ot][kt] = *(const v4s*)(qkwL + (ot*16 + m16)*32 + kt*16 + g4);
                #pragma unroll
                for (int ot = 0; ot < 2; ot++)
                #pragma unroll
                for (int nt = 0; nt < 2; nt++){
                    int nl = n0 + (wid*2 + nt)*16 + m16;
                    float4 ev = *(const float4*)((ot == 0 ? qeL : keL) + nl*16 + g4);
                    v4f a2 = (v4f){ev.x, ev.y, ev.z, ev.w};
                    #pragma unroll
                    for (int kt = 0; kt < 2; kt++)
                        a2 = MFMA16(qa[ot][kt], xh[kt][nt], a2);
                    v4s rr;
                    #pragma unroll
                    for (int i = 0; i < 4; i++) rr[i] = (short)f2bf(a2[i]);
                    *(v4s*)((ot == 0 ? p.qbf : p.kbf) + (bt*512 + nl)*16 + g4) = rr;
                }
            }
            if (t == To - 1){
                #pragma unroll 4
                for (int ot = 0; ot < 16; ot++){
                    v4s sh_[2], sl_[2];
                    #pragma unroll
                    for (int kt = 0; kt < 2; kt++){
                        sh_[kt] = *(const v4s*)(swhL + (ot*16 + m16)*32 + kt*16 + g4);
                        sl_[kt] = *(const v4s*)(swlL + (ot*16 + m16)*32 + kt*16 + g4);
                    }
                    float4 sbv = *(const float4*)(sbL + ot*16 + g4);
                    #pragma unroll
                    for (int nt = 0; nt < 2; nt++){
                        int nl = n0 + (wid*2 + nt)*16 + m16;
                        float* sp = p.skip + ((size_t)(b*512) + nl)*256 + ot*16 + g4;
                        float4 old = *(const float4*)sp;
                        v4f a3 = (v4f){old.x + sbv.x, old.y + sbv.y, old.z + sbv.z, old.w + sbv.w};
                        #pragma unroll
                        for (int kt = 0; kt < 2; kt++){
                            a3 = MFMA16(sh_[kt], xh[kt][nt], a3);
                            a3 = MFMA16(sh_[kt], xl[kt][nt], a3);
                            a3 = MFMA16(sl_[kt], xh[kt][nt], a3);
                        }
                        *(float4*)sp = make_float4(a3[0], a3[1], a3[2], a3[3]);
                    }
                }
            }
            __syncthreads();
        }
        gbar(p.bcnt, p.bgen, nb);

        if (L < 7){
            int nBC = 4*To*8;
            // ========== PHASE B: Z ==========
            for (int it = bid; it < nBC; it += nb){
                int vchunk = it & 3; int r = it >> 2; int t = r % To; int b = r / To;
                ushort_t* KS = (ushort_t*)LB;   // 512*20
                size_t bt = (size_t)(b*To + t);
                const ushort_t* kg = p.kbf + bt*8192;
                const ushort_t* qg = p.qbf + bt*8192;
                {
                    const uint2* s0 = (const uint2*)(kg + tid*16);
                    uint2* d0 = (uint2*)(KS + tid*20);
                    d0[0]=s0[0]; d0[1]=s0[1]; d0[2]=s0[2]; d0[3]=s0[3];
                    const uint2* s1 = (const uint2*)(kg + (tid+256)*16);
                    uint2* d1 = (uint2*)(KS + (tid+256)*20);
                    d1[0]=s1[0]; d1[1]=s1[1]; d1[2]=s1[2]; d1[3]=s1[3];
                }
                __syncthreads();
                #pragma unroll
                for (int vi = 0; vi < 2; vi++){
                    int vt = vchunk*8 + wid*2 + vi;
                    v4s bq = *(const v4s*)(qg + (vt*16 + m16)*16 + g4);
                    float zp = 0.f;
                    for (int wt = 0; wt < 32; wt++){
                        v4s ak = *(const v4s*)(KS + (wt*16 + m16)*20 + g4);
                        v4f s = MFMA16(ak, bq, ((v4f){0.f,0.f,0.f,0.f}));
                        zp += __expf(fminf(s[0],60.f)) + __expf(fminf(s[1],60.f))
                            + __expf(fminf(s[2],60.f)) + __expf(fminf(s[3],60.f));
                    }
                    zp += __shfl_xor(zp, 16);
                    zp += __shfl_xor(zp, 32);
                    if (lane < 16) p.rz[bt*512 + vt*16 + lane] = 1.0f/zp;
                }
                __syncthreads();
            }
            gbar(p.bcnt, p.bgen, nb);

            // ========== PHASE C: PV + gmlp + residual + BN ==========
            const float* gwL = p.gmlp_w + L*2048;
            const float* gmbL = p.gmlp_b + L*32;
            float* bnOut = p.bnsum + L*64;
            for (int it = bid; it < nBC; it += nb){
                int wc = it & 3; int r = it >> 2; int t = r % To; int b = r / To;
                ushort_t* QS = (ushort_t*)LB;                 // 512*20
                ushort_t* XT = (ushort_t*)(LB + 20480);       // 32*520
                float* rzs   = (float*)(LB + 53760);          // 512
                float* bnsh  = (float*)(LB + 55808);          // 256
                float* ABsh  = (float*)(LB + 56832);          // 64
                size_t bt = (size_t)(b*To + t);
                const ushort_t* qg = p.qbf + bt*8192;
                const ushort_t* kg = p.kbf + bt*8192;
                {
                    const uint2* s0 = (const uint2*)(qg + tid*16);
                    uint2* d0 = (uint2*)(QS + tid*20);
                    d0[0]=s0[0]; d0[1]=s0[1]; d0[2]=s0[2]; d0[3]=s0[3];
                    const uint2* s1 = (const uint2*)(qg + (tid+256)*16);
                    uint2* d1 = (uint2*)(QS + (tid+256)*20);
                    d1[0]=s1[0]; d1[1]=s1[1]; d1[2]=s1[2]; d1[3]=s1[3];
                    int c = tid >> 3, seg = tid & 7;
                    const uint4* xs = (const uint4*)(p.xbfT + bt*16384 + c*512 + seg*64);
                    uint4* xd = (uint4*)(XT + c*520 + seg*64);
                    #pragma unroll
                    for (int j = 0; j < 8; j++) xd[j] = xs[j];
                    rzs[tid] = p.rz[bt*512 + tid];
                    rzs[tid + 256] = p.rz[bt*512 + tid + 256];
                }
                if (tid < 32){
                    float A, Bc;
                    if (L == 0){ A = 1.0f; Bc = 0.0f; }
                    else {
                        float S = bnsumP[2*tid], S2 = bnsumP[2*tid + 1];
                        float m = S/cnt, var = S2/cnt - m*m;
                        A = gP[tid]*rsqrtf(var + 1e-5f);
                        Bc = bP[tid] - m*A;
                    }
                    ABsh[tid] = A; ABsh[32 + tid] = Bc;
                }
                v4s AG[2][2][2];
                #pragma unroll
                for (int pt = 0; pt < 2; pt++)
                #pragma unroll
                for (int ot = 0; ot < 2; ot++)
                #pragma unroll
                for (int ct = 0; ct < 2; ct++){
                    float4 gv = *(const float4*)(gwL + (ot*16 + m16)*64 + pt*32 + ct*16 + g4);
                    v4s rr; rr[0] = (short)f2bf(gv.x); rr[1] = (short)f2bf(gv.y);
                    rr[2] = (short)f2bf(gv.z); rr[3] = (short)f2bf(gv.w);
                    AG[pt][ot][ct] = rr;
                }
                v4f gbv[2];
                #pragma unroll
                for (int ot = 0; ot < 2; ot++) gbv[ot] = *(const v4f*)(gmbL + ot*16 + g4);
                int wt0 = wc*8 + wid*2;
                v4s bk[2];
                bk[0] = *(const v4s*)(kg + (wt0*16 + m16)*16 + g4);
                bk[1] = *(const v4s*)(kg + ((wt0+1)*16 + m16)*16 + g4);
                __syncthreads();
                v4f An[2], Bn[2];
                #pragma unroll
                for (int ot = 0; ot < 2; ot++){
                    #pragma unroll
                    for (int i = 0; i < 4; i++){
                        An[ot][i] = ABsh[ot*16 + g4 + i];
                        Bn[ot][i] = ABsh[32 + ot*16 + g4 + i];
                    }
                }
                v4f c2[2][2];
                #pragma unroll
                for (int i = 0; i < 2; i++){ c2[i][0] = (v4f){0.f,0.f,0.f,0.f}; c2[i][1] = (v4f){0.f,0.f,0.f,0.f}; }
                for (int vt = 0; vt < 32; vt++){
                    v4s aq = *(const v4s*)(QS + (vt*16 + m16)*20 + g4);
                    v4f s0 = MFMA16(aq, bk[0], ((v4f){0.f,0.f,0.f,0.f}));
                    v4f s1 = MFMA16(aq, bk[1], ((v4f){0.f,0.f,0.f,0.f}));
                    v4f rzv = *(const v4f*)(rzs + vt*16 + g4);
                    v4s p0, p1;
                    #pragma unroll
                    for (int i = 0; i < 4; i++){
                        p0[i] = (short)f2bf(__expf(fminf(s0[i],60.f)) * rzv[i]);
                        p1[i] = (short)f2bf(__expf(fminf(s1[i],60.f)) * rzv[i]);
                    }
                    #pragma unroll
                    for (int ct = 0; ct < 2; ct++){
                        v4s ax = *(const v4s*)(XT + (ct*16 + m16)*520 + vt*16 + g4);
                        c2[0][ct] = MFMA16(ax, p0, c2[0][ct]);
                        c2[1][ct] = MFMA16(ax, p1, c2[1][ct]);
                    }
                }
                float bs1[2][4], bs2[2][4];
                #pragma unroll
                for (int ot = 0; ot < 2; ot++)
                #pragma unroll
                for (int i = 0; i < 4; i++){ bs1[ot][i] = 0.f; bs2[ot][i] = 0.f; }
                #pragma unroll
                for (int wtl = 0; wtl < 2; wtl++){
                    int wt = wt0 + wtl;
                    v4s bxa[2], bx[2];
                    #pragma unroll
                    for (int ct = 0; ct < 2; ct++){
                        v4s rr;
                        #pragma unroll
                        for (int i = 0; i < 4; i++) rr[i] = (short)f2bf(c2[wtl][ct][i]);
                        bxa[ct] = rr;
                        v4s qq;
                        #pragma unroll
                        for (int i = 0; i < 4; i++) qq[i] = (short)XT[(ct*16 + g4 + i)*520 + wt*16 + m16];
                        bx[ct] = qq;
                    }
                    v4f c3[2];
                    #pragma unroll
                    for (int ot = 0; ot < 2; ot++){
                        c3[ot] = gbv[ot];
                        #pragma unroll
                        for (int ct = 0; ct < 2; ct++){
                            c3[ot] = MFMA16(AG[1][ot][ct], bxa[ct], c3[ot]);
                            c3[ot] = MFMA16(AG[0][ot][ct], bx[ct],  c3[ot]);
                        }
                    }
                    int wg = wt*16 + m16;
                    const float* resbase = xin + ((size_t)(b*Ti + t + d)*32)*512 + wg;
                    float* ybase = yb + (bt*32)*512 + wg;
                    #pragma unroll
                    for (int ot = 0; ot < 2; ot++){
                        #pragma unroll
                        for (int i = 0; i < 4; i++){
                            int outc = ot*16 + g4 + i;
                            float yv = c3[ot][i] + An[ot][i]*resbase[(size_t)outc*512] + Bn[ot][i];
                            ybase[(size_t)outc*512] = yv;
                            bs1[ot][i] += yv; bs2[ot][i] += yv*yv;
                        }
                    }
                }
                #pragma unroll
                for (int off = 1; off <= 8; off <<= 1){
                    #pragma unroll
                    for (int ot = 0; ot < 2; ot++)
                    #pragma unroll
                    for (int i = 0; i < 4; i++){
                        bs1[ot][i] += __shfl_xor(bs1[ot][i], off);
                        bs2[ot][i] += __shfl_xor(bs2[ot][i], off);
                    }
                }
                if (m16 == 0){
                    #pragma unroll
                    for (int ot = 0; ot < 2; ot++)
                    #pragma unroll
                    for (int i = 0; i < 4; i++){
                        int c = ot*16 + g4 + i;
                        bnsh[(wid*32 + c)*2 + 0] = bs1[ot][i];
                        bnsh[(wid*32 + c)*2 + 1] = bs2[ot][i];
                    }
                }
                __syncthreads();
                if (tid < 64){
                    int c = tid & 31, pp = tid >> 5;
                    float s = 0.f;
                    #pragma unroll
                    for (int w = 0; w < 4; w++) s += bnsh[(w*32 + c)*2 + pp];
                    atomicAdd(&bnOut[c*2 + pp], s);
                }
                __syncthreads();
            }
            gbar(p.bcnt, p.bgen, nb);
            float* tmp = xin; xin = yb; yb = tmp;
        }
    }

    // ================= END =================
    for (int it = bid; it < 256; it += nb){
        int nc = it & 31, b = it >> 5;
        ushort_t* SH = (ushort_t*)LB;               // 16*264
        ushort_t* SL = (ushort_t*)(LB + 8448);
        ushort_t* HH = (ushort_t*)(LB + 16896);     // 512*18
        ushort_t* HL = (ushort_t*)(LB + 35328);
        float* PS    = (float*)(LB + 53760);        // [4][16][17]
        int n0 = nc*16;
        {
            int n = tid >> 4, s = tid & 15;
            const float4* src = (const float4*)(p.skip + ((size_t)(b*512 + n0 + n))*256 + s*16);
            #pragma unroll
            for (int j = 0; j < 4; j++){
                float4 v4_ = src[j];
                float vv[4] = {v4_.x, v4_.y, v4_.z, v4_.w};
                #pragma unroll
                for (int e = 0; e < 4; e++){
                    float v = fmaxf(vv[e], 0.f);
                    ushort_t h = f2bf(v);
                    SH[n*264 + s*16 + j*4 + e] = h;
                    SL[n*264 + s*16 + j*4 + e] = f2bf(v - bf2f(h));
                }
            }
        }
        __syncthreads();
        v4f acc[8];
        #pragma unroll
        for (int nt = 0; nt < 8; nt++){
            float bo = p.b1[(wid*8 + nt)*16 + m16];
            acc[nt] = (v4f){bo, bo, bo, bo};
        }
        for (int kk = 0; kk < 16; kk++){
            v4s ahi = *(const v4s*)(SH + m16*264 + kk*16 + g4);
            v4s alo = *(const v4s*)(SL + m16*264 + kk*16 + g4);
            #pragma unroll
            for (int nt = 0; nt < 8; nt++){
                int ob = ((wid*8 + nt)*16 + kk)*256;
                v4s bhi = *(const v4s*)(p.w1ph + ob + m16*16 + g4);
                v4s blo = *(const v4s*)(p.w1pl + ob + m16*16 + g4);
                acc[nt] = MFMA16(ahi, bhi, acc[nt]);
                acc[nt] = MFMA16(ahi, blo, acc[nt]);
                acc[nt] = MFMA16(alo, bhi, acc[nt]);
            }
        }
        #pragma unroll
        for (int nt = 0; nt < 8; nt++){
            int o = (wid*8 + nt)*16 + m16;
            #pragma unroll
            for (int i = 0; i < 4; i++){
                float v = fmaxf(acc[nt][i], 0.f);
                ushort_t h = f2bf(v);
                HH[o*18 + g4 + i] = h;
                HL[o*18 + g4 + i] = f2bf(v - bf2f(h));
            }
        }
        __syncthreads();
        v4f a4 = (v4f){0.f, 0.f, 0.f, 0.f};
        for (int q = 0; q < 8; q++){
            int kt = wid*8 + q;
            v4s wh = *(const v4s*)(p.w2ph + kt*256 + m16*16 + g4);
            v4s wl = *(const v4s*)(p.w2pl + kt*256 + m16*16 + g4);
            v4s hh, hl;
            #pragma unroll
            for (int i = 0; i < 4; i++){
                int k = kt*16 + g4 + i;
                hh[i] = (short)HH[k*18 + m16];
                hl[i] = (short)HL[k*18 + m16];
            }
            a4 = MFMA16(wh, hh, a4);
            a4 = MFMA16(wh, hl, a4);
            a4 = MFMA16(wl, hh, a4);
        }
        #pragma unroll
        for (int i = 0; i < 4; i++) PS[(wid*16 + g4 + i)*17 + m16] = a4[i];
        __syncthreads();
        if (wid == 0){
            #pragma unroll
            for (int i = 0; i < 4; i++){
                int od = g4 + i;
                if (od < 12){
                    float v = p.b2[od] + PS[(0*16 + od)*17 + m16] + PS[(1*16 + od)*17 + m16]
                            + PS[(2*16 + od)*17 + m16] + PS[(3*16 + od)*17 + m16];
                    p.out[((size_t)(b*12 + od))*512 + n0 + m16] = v;
                }
            }
        }
        __syncthreads();
    }
}

extern "C" void kernel_launch(void* const* d_in, const int* in_sizes, int n_in,
                              void* d_out, int out_size, void* d_ws, size_t ws_size,
                              hipStream_t stream)
{
    (void)in_sizes; (void)n_in; (void)out_size; (void)ws_size;
    float* W = (float*)d_ws;
    size_t off = 0;
    float* skip = W + off; off += (size_t)8*512*256;
    float* bnsum= W + off; off += (size_t)7*64;       // contiguous with skip (zeroed together)
    float* bufA = W + off; off += (size_t)8*13*32*512;
    float* bufB = W + off; off += (size_t)8*13*32*512;
    float* qe   = W + off; off += (size_t)8*512*16;
    float* ke   = W + off; off += (size_t)8*512*16;
    float* rz   = W + off; off += (size_t)8*12*512;
    unsigned* bstate = (unsigned*)(W + off); off += 16;
    ushort_t* xbfT = (ushort_t*)(W + off); off += (size_t)8*12*32*512/2;
    ushort_t* qbf  = (ushort_t*)(W + off); off += (size_t)8*12*512*16/2;
    ushort_t* kbf  = (ushort_t*)(W + off); off += (size_t)8*12*512*16/2;
    ushort_t* cwh  = (ushort_t*)(W + off); off += (size_t)32768/2;
    ushort_t* cwl  = (ushort_t*)(W + off); off += (size_t)32768/2;
    ushort_t* qkw  = (ushort_t*)(W + off); off += (size_t)8192/2;
    ushort_t* swbh = (ushort_t*)(W + off); off += (size_t)65536/2;
    ushort_t* swbl = (ushort_t*)(W + off); off += (size_t)65536/2;
    ushort_t* w1ph = (ushort_t*)(W + off); off += (size_t)512*256/2;
    ushort_t* w1pl = (ushort_t*)(W + off); off += (size_t)512*256/2;
    ushort_t* w2ph = (ushort_t*)(W + off); off += (size_t)16*512/2;
    ushort_t* w2pl = (ushort_t*)(W + off); off += (size_t)16*512/2;

    // barrier state must start at {cnt=0, gen=anything}; zero it each launch (stream-ordered)
    hipMemsetAsync(bstate, 0, 64, stream);

    MegaParams p;
    p.inp = (const float*)d_in[0];
    p.gat = (const float*)d_in[1];
    p.start_w = (const float*)d_in[2];
    p.start_b = (const float*)d_in[3];
    p.filt_w = (const float*)d_in[4];
    p.filt_b = (const float*)d_in[5];
    p.gate_w = (const float*)d_in[6];
    p.gate_b = (const float*)d_in[7];
    p.skip_w = (const float*)d_in[8];
    p.skip_b = (const float*)d_in[9];
    p.q_w = (const float*)d_in[10];
    p.q_b = (const float*)d_in[11];
    p.k_w = (const float*)d_in[12];
    p.k_b = (const float*)d_in[13];
    p.gmlp_w = (const float*)d_in[14];
    p.gmlp_b = (const float*)d_in[15];
    p.bn_g = (const float*)d_in[16];
    p.bn_b = (const float*)d_in[17];
    p.w1 = (const float*)d_in[18];
    p.b1 = (const float*)d_in[19];
    p.w2 = (const float*)d_in[20];
    p.b2 = (const float*)d_in[21];
    p.out = (float*)d_out;
    p.skip = skip; p.bnsum = bnsum; p.bufA = bufA; p.bufB = bufB;
    p.qe = qe; p.ke = ke; p.rz = rz;
    p.xbfT = xbfT; p.qbf = qbf; p.kbf = kbf;
    p.cwh = cwh; p.cwl = cwl; p.qkw = qkw; p.swh = swbh; p.swl = swbl;
    p.w1ph = w1ph; p.w1pl = w1pl; p.w2ph = w2ph; p.w2pl = w2pl;
    p.bcnt = bstate; p.bgen = bstate + 1;

    int nPerCU = 0;
    hipOccupancyMaxActiveBlocksPerMultiprocessor(&nPerCU, k_mega, 256, 0);
    if (nPerCU < 1) nPerCU = 1;
    if (nPerCU > 2) nPerCU = 2;
    int grid = nPerCU * 256;   // guaranteed co-resident: LDS 58 KB -> <=2 blocks/CU, 256 CUs

    k_mega<<<dim3(grid), dim3(256), 0, stream>>>(p);
}

// Round 12
// 529.797 us; speedup vs baseline: 4.3175x; 4.3175x over previous
//
#include <hip/hip_runtime.h>
#include <math.h>

// Sizes: B=8, IN=2, N=512, T_IN=13, RC=DC=32, SC=256, EC=512, EMB=16, DATT=16, L=8

typedef short v4s __attribute__((ext_vector_type(4)));
typedef float v4f __attribute__((ext_vector_type(4)));
typedef unsigned short ushort_t;

#define MFMA16(a,b,c) __builtin_amdgcn_mfma_f32_16x16x16bf16_1k(a, b, c, 0, 0, 0)

__device__ inline ushort_t f2bf(float f){
    unsigned int u = __builtin_bit_cast(unsigned int, f);
    u += 0x7FFFu + ((u >> 16) & 1u);
    return (ushort_t)(u >> 16);
}
__device__ inline float bf2f(ushort_t h){
    return __builtin_bit_cast(float, ((unsigned int)h) << 16);
}

// One fused prep kernel: zeros (skip+bnsum), qe/ke emb, start pw, all weight splits/permutes.
__global__ void k_prep(
    const float* __restrict__ inp, const float* __restrict__ start_w, const float* __restrict__ start_b,
    const float* __restrict__ gat,
    const float* __restrict__ qw, const float* __restrict__ qb,
    const float* __restrict__ kw, const float* __restrict__ kb,
    const float* __restrict__ filt_w, const float* __restrict__ gate_w,
    const float* __restrict__ skip_w,
    const float* __restrict__ w1, const float* __restrict__ w2,
    float* __restrict__ zero_base,
    float* __restrict__ qe, float* __restrict__ ke, float* __restrict__ x0,
    ushort_t* __restrict__ cwh, ushort_t* __restrict__ cwl, ushort_t* __restrict__ qkw,
    ushort_t* __restrict__ swh, ushort_t* __restrict__ swl,
    ushort_t* __restrict__ w1ph, ushort_t* __restrict__ w1pl,
    ushort_t* __restrict__ w2ph, ushort_t* __restrict__ w2pl)
{
    const int E0 = 1049024;            // skip (1048576) + bnsum (448) zeros
    const int E1 = E0 + 131072;        // emb
    const int E2 = E1 + 1703936;       // start
    const int E3 = E2 + 32768;         // conv w
    const int E4 = E3 + 8192;          // qk w
    const int E5 = E4 + 65536;         // skip w
    const int E6 = E5 + 131072;        // w1 permuted
    const int E7 = E6 + 8192;          // w2 permuted
    int idx = blockIdx.x*256 + threadIdx.x;
    if (idx < E0){
        zero_base[idx] = 0.0f;
    } else if (idx < E1){
        int id = idx - E0;
        const int total = 8*512*16;
        bool isK = id >= total;
        if (isK) id -= total;
        int dq = id & 15; int n = (id >> 4) & 511; int l = id >> 13;
        const float* w = isK ? kw : qw;
        const float* bi = isK ? kb : qb;
        float acc = bi[l*16 + dq];
        const float* wrow = w + (l*16 + dq)*48 + 32;
        #pragma unroll
        for (int e = 0; e < 16; e++) acc += wrow[e] * gat[e*512 + n];
        (isK ? ke : qe)[(l*512 + n)*16 + dq] = isK ? acc : acc*0.25f;
    } else if (idx < E2){
        int id = idx - E1;
        int n = id & 511; int c = (id >> 9) & 31; int r = id >> 14;
        int t = r % 13; int b = r / 13;
        float v0 = inp[((b*2 + 0)*512 + n)*13 + t];
        float v1 = inp[((b*2 + 1)*512 + n)*13 + t];
        x0[id] = start_b[c] + start_w[c*2 + 0]*v0 + start_w[c*2 + 1]*v1;
    } else if (idx < E3){
        int id = idx - E2;
        int k = id & 63, o = (id >> 6) & 63, l = id >> 12;
        int c = k & 31, tap = k >> 5;
        float w = (o < 32) ? filt_w[((l*32 + o)*32 + c)*2 + tap]
                           : gate_w[((l*32 + (o-32))*32 + c)*2 + tap];
        ushort_t hi = f2bf(w);
        cwh[id] = hi; cwl[id] = f2bf(w - bf2f(hi));
    } else if (idx < E4){
        int id = idx - E3;
        int c = id & 31, j = (id >> 5) & 31, l = id >> 10;
        float w = (j < 16) ? qw[(l*16 + j)*48 + c]*0.25f : kw[(l*16 + (j-16))*48 + c];
        qkw[id] = f2bf(w);
    } else if (idx < E5){
        int id = idx - E4;
        float w = skip_w[id];
        ushort_t hi = f2bf(w);
        swh[id] = hi; swl[id] = f2bf(w - bf2f(hi));
    } else if (idx < E6){
        int id = idx - E5;
        int j = id & 15, mm = (id >> 4) & 15, kk = (id >> 8) & 15, ot = id >> 12;
        float w = w1[((size_t)(ot*16 + mm))*256 + kk*16 + j];
        ushort_t hi = f2bf(w);
        w1ph[id] = hi; w1pl[id] = f2bf(w - bf2f(hi));
    } else if (idx < E7){
        int id = idx - E6;
        int j = id & 15, mm = (id >> 4) & 15, kt = id >> 8;
        float w = (mm < 12) ? w2[mm*512 + kt*16 + j] : 0.0f;
        ushort_t hi = f2bf(w);
        w2ph[id] = hi; w2pl[id] = f2bf(w - bf2f(hi));
    }
}

// MFMA gated conv + q/k projection + skip matmul. Block = (nchunk of 128, t, b), 256 thr.
__global__ __launch_bounds__(256) void k_gated_mfma(
    const float* __restrict__ xin, int Tin, int d, int Tout,
    const float* __restrict__ bnsumP, const float* __restrict__ bnG,
    const float* __restrict__ bnB, int ident, float cnt,
    const ushort_t* __restrict__ cwh, const ushort_t* __restrict__ cwl,
    const float* __restrict__ fb, const float* __restrict__ gb,
    const ushort_t* __restrict__ qkw,
    const float* __restrict__ qe, const float* __restrict__ ke,
    const ushort_t* __restrict__ swh, const ushort_t* __restrict__ swl,
    const float* __restrict__ sb,
    float* __restrict__ skip,
    ushort_t* __restrict__ xbfT, ushort_t* __restrict__ qbf, ushort_t* __restrict__ kbf,
    int do_qk)
{
    __shared__ unsigned int XBP[64*129];   // [k 64][n 128+1] packed (hi | lo<<16)
    __shared__ float ABsh[64];
    int tid = threadIdx.x;
    int nch = blockIdx.x, t = blockIdx.y, b = blockIdx.z;
    size_t bt = (size_t)(b*Tout + t);
    int n0 = nch*128;
    int lane = tid & 63, wid = tid >> 6;
    int m16 = lane & 15, g4 = (lane >> 4)*4;

    if (tid < 32){
        float A, Bc;
        if (ident){ A = 1.0f; Bc = 0.0f; }
        else {
            float S = bnsumP[2*tid], S2 = bnsumP[2*tid + 1];
            float m = S/cnt, var = S2/cnt - m*m;
            A = bnG[tid]*rsqrtf(var + 1e-5f);
            Bc = bnB[tid] - m*A;
        }
        ABsh[tid] = A; ABsh[32 + tid] = Bc;
    }
    __syncthreads();

    #pragma unroll
    for (int kk = 0; kk < 16; kk++){
        int k = wid*16 + kk;
        int c = k & 31, tap = k >> 5;
        const float* src = xin + ((size_t)(b*Tin + t + tap*d)*32 + c)*512 + n0 + lane;
        float An = ABsh[c], Bn = ABsh[32 + c];
        #pragma unroll
        for (int h = 0; h < 2; h++){
            float xn = An*src[h*64] + Bn;
            ushort_t hi = f2bf(xn);
            ushort_t lo = f2bf(xn - bf2f(hi));
            XBP[k*129 + h*64 + lane] = (unsigned int)hi | ((unsigned int)lo << 16);
        }
    }
    v4s ah[4][4], al[4][4];
    #pragma unroll
    for (int ot = 0; ot < 4; ot++)
    #pragma unroll
    for (int kt = 0; kt < 4; kt++){
        ah[ot][kt] = *(const v4s*)(cwh + (ot*16 + m16)*64 + kt*16 + g4);
        al[ot][kt] = *(const v4s*)(cwl + (ot*16 + m16)*64 + kt*16 + g4);
    }
    v4f acc[4][2];
    #pragma unroll
    for (int ot = 0; ot < 4; ot++){
        float4 bv = *(const float4*)((ot < 2 ? fb + ot*16 : gb + (ot-2)*16) + g4);
        acc[ot][0] = (v4f){bv.x, bv.y, bv.z, bv.w};
        acc[ot][1] = (v4f){bv.x, bv.y, bv.z, bv.w};
    }
    __syncthreads();
    v4s bh[2][4], bl[2][4];
    #pragma unroll
    for (int nt = 0; nt < 2; nt++){
        int nl = (wid*2 + nt)*16 + m16;
        #pragma unroll
        for (int kt = 0; kt < 4; kt++){
            unsigned int u0 = XBP[(kt*16 + g4 + 0)*129 + nl];
            unsigned int u1 = XBP[(kt*16 + g4 + 1)*129 + nl];
            unsigned int u2 = XBP[(kt*16 + g4 + 2)*129 + nl];
            unsigned int u3 = XBP[(kt*16 + g4 + 3)*129 + nl];
            v4s hh, ll;
            hh[0] = (short)(u0 & 0xffffu); ll[0] = (short)(u0 >> 16);
            hh[1] = (short)(u1 & 0xffffu); ll[1] = (short)(u1 >> 16);
            hh[2] = (short)(u2 & 0xffffu); ll[2] = (short)(u2 >> 16);
            hh[3] = (short)(u3 & 0xffffu); ll[3] = (short)(u3 >> 16);
            bh[nt][kt] = hh; bl[nt][kt] = ll;
        }
    }
    #pragma unroll
    for (int kt = 0; kt < 4; kt++)
    #pragma unroll
    for (int ot = 0; ot < 4; ot++)
    #pragma unroll
    for (int nt = 0; nt < 2; nt++){
        acc[ot][nt] = MFMA16(ah[ot][kt], bh[nt][kt], acc[ot][nt]);
        acc[ot][nt] = MFMA16(ah[ot][kt], bl[nt][kt], acc[ot][nt]);
        acc[ot][nt] = MFMA16(al[ot][kt], bh[nt][kt], acc[ot][nt]);
    }
    v4s xh[2][2], xl[2][2];
    #pragma unroll
    for (int ct = 0; ct < 2; ct++)
    #pragma unroll
    for (int nt = 0; nt < 2; nt++){
        v4s hh, ll;
        #pragma unroll
        for (int i = 0; i < 4; i++){
            float f = acc[ct][nt][i], g = acc[ct+2][nt][i];
            float e2 = __expf(2.0f*f);
            float th = 1.0f - 2.0f/(e2 + 1.0f);
            float sg = 1.0f/(1.0f + __expf(-g));
            float v = th*sg;
            ushort_t hi = f2bf(v);
            hh[i] = (short)hi; ll[i] = (short)f2bf(v - bf2f(hi));
        }
        xh[ct][nt] = hh; xl[ct][nt] = ll;
    }
    if (do_qk){
        #pragma unroll
        for (int ct = 0; ct < 2; ct++)
        #pragma unroll
        for (int nt = 0; nt < 2; nt++){
            int nl = n0 + (wid*2 + nt)*16 + m16;
            #pragma unroll
            for (int i = 0; i < 4; i++)
                xbfT[(bt*32 + ct*16 + g4 + i)*512 + nl] = (ushort_t)xh[ct][nt][i];
        }
        v4s qa[2][2];
        #pragma unroll
        for (int ot = 0; ot < 2; ot++)
        #pragma unroll
        for (int kt = 0; kt < 2; kt++)
            qa[ot][kt] = *(const v4s*)(qkw + (ot*16 + m16)*32 + kt*16 + g4);
        #pragma unroll
        for (int ot = 0; ot < 2; ot++)
        #pragma unroll
        for (int nt = 0; nt < 2; nt++){
            int nl = n0 + (wid*2 + nt)*16 + m16;
            float4 ev = *(const float4*)((ot == 0 ? qe : ke) + nl*16 + g4);
            v4f a2 = (v4f){ev.x, ev.y, ev.z, ev.w};
            #pragma unroll
            for (int kt = 0; kt < 2; kt++)
                a2 = MFMA16(qa[ot][kt], xh[kt][nt], a2);
            v4s r;
            #pragma unroll
            for (int i = 0; i < 4; i++) r[i] = (short)f2bf(a2[i]);
            *(v4s*)((ot == 0 ? qbf : kbf) + (bt*512 + nl)*16 + g4) = r;
        }
    }
    if (t == Tout - 1){
        #pragma unroll 4
        for (int ot = 0; ot < 16; ot++){
            v4s sh_[2], sl_[2];
            #pragma unroll
            for (int kt = 0; kt < 2; kt++){
                sh_[kt] = *(const v4s*)(swh + (ot*16 + m16)*32 + kt*16 + g4);
                sl_[kt] = *(const v4s*)(swl + (ot*16 + m16)*32 + kt*16 + g4);
            }
            float4 sbv = *(const float4*)(sb + ot*16 + g4);
            #pragma unroll
            for (int nt = 0; nt < 2; nt++){
                int nl = n0 + (wid*2 + nt)*16 + m16;
                float* sp = skip + ((size_t)(b*512) + nl)*256 + ot*16 + g4;
                float4 old = *(const float4*)sp;
                v4f a3 = (v4f){old.x + sbv.x, old.y + sbv.y, old.z + sbv.z, old.w + sbv.w};
                #pragma unroll
                for (int kt = 0; kt < 2; kt++){
                    a3 = MFMA16(sh_[kt], xh[kt][nt], a3);
                    a3 = MFMA16(sh_[kt], xl[kt][nt], a3);
                    a3 = MFMA16(sl_[kt], xh[kt][nt], a3);
                }
                *(float4*)sp = make_float4(a3[0], a3[1], a3[2], a3[3]);
            }
        }
    }
}

// Fused Z + PV + gmlp + residual + BN partials. Block = (wchunk of 128, t, b), 256 thr.
// K, Q, XT all staged in LDS; Z computed in-block (4x duplicated, cheap); rz lives in LDS.
__global__ __launch_bounds__(256) void k_zpv(
    const ushort_t* __restrict__ qbf, const ushort_t* __restrict__ kbf,
    const ushort_t* __restrict__ xbfT,
    const float* __restrict__ xin, int Tin, int d, int Tout,
    const float* __restrict__ bnsumP, const float* __restrict__ bnG,
    const float* __restrict__ bnB, int ident, float cnt,
    const float* __restrict__ gw, const float* __restrict__ gb,
    float* __restrict__ y, float* __restrict__ bnsumOut)
{
    __shared__ __align__(16) char LB[77568];
    ushort_t* KS = (ushort_t*)LB;                 // 512*20 = 20480 B
    ushort_t* QS = (ushort_t*)(LB + 20480);       // 20480 B
    ushort_t* XT = (ushort_t*)(LB + 40960);       // 32*520*2 = 33280 B
    float* rzs   = (float*)(LB + 74240);          // 512*4
    float* bnsh  = (float*)(LB + 76288);          // 256*4
    float* ABsh  = (float*)(LB + 77312);          // 64*4
    int tid = threadIdx.x;
    int wc = blockIdx.x, t = blockIdx.y, b = blockIdx.z;
    size_t bt = (size_t)(b*Tout + t);
    const ushort_t* qg = qbf + bt*8192;
    const ushort_t* kg = kbf + bt*8192;
    int lane = tid & 63, wid = tid >> 6;
    int m16 = lane & 15, g4 = (lane >> 4)*4;
    {
        const uint2* s0 = (const uint2*)(qg + tid*16);
        uint2* d0 = (uint2*)(QS + tid*20);
        d0[0]=s0[0]; d0[1]=s0[1]; d0[2]=s0[2]; d0[3]=s0[3];
        const uint2* s1 = (const uint2*)(qg + (tid+256)*16);
        uint2* d1 = (uint2*)(QS + (tid+256)*20);
        d1[0]=s1[0]; d1[1]=s1[1]; d1[2]=s1[2]; d1[3]=s1[3];
        const uint2* s2 = (const uint2*)(kg + tid*16);
        uint2* d2 = (uint2*)(KS + tid*20);
        d2[0]=s2[0]; d2[1]=s2[1]; d2[2]=s2[2]; d2[3]=s2[3];
        const uint2* s3 = (const uint2*)(kg + (tid+256)*16);
        uint2* d3 = (uint2*)(KS + (tid+256)*20);
        d3[0]=s3[0]; d3[1]=s3[1]; d3[2]=s3[2]; d3[3]=s3[3];
        int c = tid >> 3, seg = tid & 7;
        const uint4* xs = (const uint4*)(xbfT + bt*16384 + c*512 + seg*64);
        uint4* xd = (uint4*)(XT + c*520 + seg*64);
        #pragma unroll
        for (int j = 0; j < 8; j++) xd[j] = xs[j];
    }
    if (tid < 32){
        float A, Bc;
        if (ident){ A = 1.0f; Bc = 0.0f; }
        else {
            float S = bnsumP[2*tid], S2 = bnsumP[2*tid + 1];
            float m = S/cnt, var = S2/cnt - m*m;
            A = bnG[tid]*rsqrtf(var + 1e-5f);
            Bc = bnB[tid] - m*A;
        }
        ABsh[tid] = A; ABsh[32 + tid] = Bc;
    }
    // gmlp weight frags from global (L2-hot) while staging lands
    v4s AG[2][2][2];
    #pragma unroll
    for (int pt = 0; pt < 2; pt++)
    #pragma unroll
    for (int ot = 0; ot < 2; ot++)
    #pragma unroll
    for (int ct = 0; ct < 2; ct++){
        float4 gv = *(const float4*)(gw + (ot*16 + m16)*64 + pt*32 + ct*16 + g4);
        v4s r; r[0] = (short)f2bf(gv.x); r[1] = (short)f2bf(gv.y);
        r[2] = (short)f2bf(gv.z); r[3] = (short)f2bf(gv.w);
        AG[pt][ot][ct] = r;
    }
    v4f gbv[2];
    #pragma unroll
    for (int ot = 0; ot < 2; ot++) gbv[ot] = *(const v4f*)(gb + ot*16 + g4);
    __syncthreads();

    // ---- Z phase: all 512 rows, wave wid owns v-tiles wid*8..wid*8+7 ----
    #pragma unroll
    for (int vi = 0; vi < 8; vi++){
        int vt = wid*8 + vi;
        v4s bq = *(const v4s*)(QS + (vt*16 + m16)*20 + g4);
        float zp = 0.f;
        for (int wt = 0; wt < 32; wt++){
            v4s ak = *(const v4s*)(KS + (wt*16 + m16)*20 + g4);
            v4f s = MFMA16(ak, bq, ((v4f){0.f,0.f,0.f,0.f}));
            zp += __expf(fminf(s[0],60.f)) + __expf(fminf(s[1],60.f))
                + __expf(fminf(s[2],60.f)) + __expf(fminf(s[3],60.f));
        }
        zp += __shfl_xor(zp, 16);
        zp += __shfl_xor(zp, 32);
        if (lane < 16) rzs[vt*16 + lane] = 1.0f/zp;
    }
    __syncthreads();

    // ---- PV phase ----
    v4f An[2], Bn[2];
    #pragma unroll
    for (int ot = 0; ot < 2; ot++){
        #pragma unroll
        for (int i = 0; i < 4; i++){
            An[ot][i] = ABsh[ot*16 + g4 + i];
            Bn[ot][i] = ABsh[32 + ot*16 + g4 + i];
        }
    }
    int wt0 = wc*8 + wid*2;
    v4s bk[2];
    bk[0] = *(const v4s*)(KS + (wt0*16 + m16)*20 + g4);
    bk[1] = *(const v4s*)(KS + ((wt0+1)*16 + m16)*20 + g4);
    v4f c2[2][2];
    #pragma unroll
    for (int i = 0; i < 2; i++){ c2[i][0] = (v4f){0.f,0.f,0.f,0.f}; c2[i][1] = (v4f){0.f,0.f,0.f,0.f}; }
    for (int vt = 0; vt < 32; vt++){
        v4s aq = *(const v4s*)(QS + (vt*16 + m16)*20 + g4);
        v4f s0 = MFMA16(aq, bk[0], ((v4f){0.f,0.f,0.f,0.f}));
        v4f s1 = MFMA16(aq, bk[1], ((v4f){0.f,0.f,0.f,0.f}));
        v4f rzv = *(const v4f*)(rzs + vt*16 + g4);
        v4s p0, p1;
        #pragma unroll
        for (int i = 0; i < 4; i++){
            p0[i] = (short)f2bf(__expf(fminf(s0[i],60.f)) * rzv[i]);
            p1[i] = (short)f2bf(__expf(fminf(s1[i],60.f)) * rzv[i]);
        }
        #pragma unroll
        for (int ct = 0; ct < 2; ct++){
            v4s ax = *(const v4s*)(XT + (ct*16 + m16)*520 + vt*16 + g4);
            c2[0][ct] = MFMA16(ax, p0, c2[0][ct]);
            c2[1][ct] = MFMA16(ax, p1, c2[1][ct]);
        }
    }
    float bs1[2][4], bs2[2][4];
    #pragma unroll
    for (int ot = 0; ot < 2; ot++)
    #pragma unroll
    for (int i = 0; i < 4; i++){ bs1[ot][i] = 0.f; bs2[ot][i] = 0.f; }
    #pragma unroll
    for (int wtl = 0; wtl < 2; wtl++){
        int wt = wt0 + wtl;
        v4s bxa[2], bx[2];
        #pragma unroll
        for (int ct = 0; ct < 2; ct++){
            v4s r;
            #pragma unroll
            for (int i = 0; i < 4; i++) r[i] = (short)f2bf(c2[wtl][ct][i]);
            bxa[ct] = r;
            v4s q;
            #pragma unroll
            for (int i = 0; i < 4; i++) q[i] = (short)XT[(ct*16 + g4 + i)*520 + wt*16 + m16];
            bx[ct] = q;
        }
        v4f c3[2];
        #pragma unroll
        for (int ot = 0; ot < 2; ot++){
            c3[ot] = gbv[ot];
            #pragma unroll
            for (int ct = 0; ct < 2; ct++){
                c3[ot] = MFMA16(AG[1][ot][ct], bxa[ct], c3[ot]);
                c3[ot] = MFMA16(AG[0][ot][ct], bx[ct],  c3[ot]);
            }
        }
        int wg = wt*16 + m16;
        const float* resbase = xin + ((size_t)(b*Tin + t + d)*32)*512 + wg;
        float* ybase = y + (bt*32)*512 + wg;
        #pragma unroll
        for (int ot = 0; ot < 2; ot++){
            #pragma unroll
            for (int i = 0; i < 4; i++){
                int outc = ot*16 + g4 + i;
                float yv = c3[ot][i] + An[ot][i]*resbase[(size_t)outc*512] + Bn[ot][i];
                ybase[(size_t)outc*512] = yv;
                bs1[ot][i] += yv; bs2[ot][i] += yv*yv;
            }
        }
    }
    #pragma unroll
    for (int off = 1; off <= 8; off <<= 1){
        #pragma unroll
        for (int ot = 0; ot < 2; ot++)
        #pragma unroll
        for (int i = 0; i < 4; i++){
            bs1[ot][i] += __shfl_xor(bs1[ot][i], off);
            bs2[ot][i] += __shfl_xor(bs2[ot][i], off);
        }
    }
    if (m16 == 0){
        #pragma unroll
        for (int ot = 0; ot < 2; ot++)
        #pragma unroll
        for (int i = 0; i < 4; i++){
            int c = ot*16 + g4 + i;
            bnsh[(wid*32 + c)*2 + 0] = bs1[ot][i];
            bnsh[(wid*32 + c)*2 + 1] = bs2[ot][i];
        }
    }
    __syncthreads();
    if (tid < 64){
        int c = tid & 31, pp = tid >> 5;
        float s = 0.f;
        #pragma unroll
        for (int w = 0; w < 4; w++) s += bnsh[(w*32 + c)*2 + pp];
        atomicAdd(&bnsumOut[c*2 + pp], s);
    }
}

// Fused end: relu(skip)->split->GEMM1(MFMA, permuted w1)->relu->GEMM2(all waves)->out.
__global__ __launch_bounds__(256) void k_end_all(
    const float* __restrict__ skip,
    const ushort_t* __restrict__ w1ph, const ushort_t* __restrict__ w1pl,
    const float* __restrict__ b1,
    const ushort_t* __restrict__ w2ph, const ushort_t* __restrict__ w2pl,
    const float* __restrict__ b2, float* __restrict__ out)
{
    __shared__ ushort_t SH[16*264], SL[16*264];
    __shared__ ushort_t HH[512*18], HL[512*18];
    __shared__ float PS[4][16][17];
    int tid = threadIdx.x;
    int nc = blockIdx.x, b = blockIdx.y;
    int n0 = nc*16;
    {
        int n = tid >> 4, s = tid & 15;
        const float4* src = (const float4*)(skip + ((size_t)(b*512 + n0 + n))*256 + s*16);
        #pragma unroll
        for (int j = 0; j < 4; j++){
            float4 v4_ = src[j];
            float vv[4] = {v4_.x, v4_.y, v4_.z, v4_.w};
            #pragma unroll
            for (int e = 0; e < 4; e++){
                float v = fmaxf(vv[e], 0.f);
                ushort_t h = f2bf(v);
                SH[n*264 + s*16 + j*4 + e] = h;
                SL[n*264 + s*16 + j*4 + e] = f2bf(v - bf2f(h));
            }
        }
    }
    __syncthreads();
    int l = tid & 63, wid = tid >> 6;
    int m16 = l & 15, g4 = (l >> 4)*4;
    v4f acc[8];
    #pragma unroll
    for (int nt = 0; nt < 8; nt++){
        float bo = b1[(wid*8 + nt)*16 + m16];
        acc[nt] = (v4f){bo, bo, bo, bo};
    }
    for (int kk = 0; kk < 16; kk++){
        v4s ahi = *(const v4s*)(SH + m16*264 + kk*16 + g4);
        v4s alo = *(const v4s*)(SL + m16*264 + kk*16 + g4);
        #pragma unroll
        for (int nt = 0; nt < 8; nt++){
            int ob = ((wid*8 + nt)*16 + kk)*256;
            v4s bhi = *(const v4s*)(w1ph + ob + m16*16 + g4);
            v4s blo = *(const v4s*)(w1pl + ob + m16*16 + g4);
            acc[nt] = MFMA16(ahi, bhi, acc[nt]);
            acc[nt] = MFMA16(ahi, blo, acc[nt]);
            acc[nt] = MFMA16(alo, bhi, acc[nt]);
        }
    }
    #pragma unroll
    for (int nt = 0; nt < 8; nt++){
        int o = (wid*8 + nt)*16 + m16;
        #pragma unroll
        for (int i = 0; i < 4; i++){
            float v = fmaxf(acc[nt][i], 0.f);
            ushort_t h = f2bf(v);
            HH[o*18 + g4 + i] = h;
            HL[o*18 + g4 + i] = f2bf(v - bf2f(h));
        }
    }
    __syncthreads();
    v4f a4 = (v4f){0.f, 0.f, 0.f, 0.f};
    for (int q = 0; q < 8; q++){
        int kt = wid*8 + q;
        v4s wh = *(const v4s*)(w2ph + kt*256 + m16*16 + g4);
        v4s wl = *(const v4s*)(w2pl + kt*256 + m16*16 + g4);
        v4s hh, hl;
        #pragma unroll
        for (int i = 0; i < 4; i++){
            int k = kt*16 + g4 + i;
            hh[i] = (short)HH[k*18 + m16];
            hl[i] = (short)HL[k*18 + m16];
        }
        a4 = MFMA16(wh, hh, a4);
        a4 = MFMA16(wh, hl, a4);
        a4 = MFMA16(wl, hh, a4);
    }
    #pragma unroll
    for (int i = 0; i < 4; i++) PS[wid][g4 + i][m16] = a4[i];
    __syncthreads();
    if (wid == 0){
        #pragma unroll
        for (int i = 0; i < 4; i++){
            int od = g4 + i;
            if (od < 12){
                float v = b2[od] + PS[0][od][m16] + PS[1][od][m16]
                        + PS[2][od][m16] + PS[3][od][m16];
                out[((size_t)(b*12 + od))*512 + n0 + m16] = v;
            }
        }
    }
}

extern "C" void kernel_launch(void* const* d_in, const int* in_sizes, int n_in,
                              void* d_out, int out_size, void* d_ws, size_t ws_size,
                              hipStream_t stream)
{
    (void)in_sizes; (void)n_in; (void)out_size; (void)ws_size;
    const float* input  = (const float*)d_in[0];
    const float* gat    = (const float*)d_in[1];
    const float* start_w= (const float*)d_in[2];
    const float* start_b= (const float*)d_in[3];
    const float* filt_w = (const float*)d_in[4];
    const float* filt_b = (const float*)d_in[5];
    const float* gate_w = (const float*)d_in[6];
    const float* gate_b = (const float*)d_in[7];
    const float* skip_w = (const float*)d_in[8];
    const float* skip_b = (const float*)d_in[9];
    const float* q_w    = (const float*)d_in[10];
    const float* q_b    = (const float*)d_in[11];
    const float* k_w    = (const float*)d_in[12];
    const float* k_b    = (const float*)d_in[13];
    const float* gmlp_w = (const float*)d_in[14];
    const float* gmlp_b = (const float*)d_in[15];
    const float* bn_g   = (const float*)d_in[16];
    const float* bn_b   = (const float*)d_in[17];
    const float* end1_w = (const float*)d_in[18];
    const float* end1_b = (const float*)d_in[19];
    const float* end2_w = (const float*)d_in[20];
    const float* end2_b = (const float*)d_in[21];
    float* out = (float*)d_out;

    float* W = (float*)d_ws;
    size_t off = 0;
    float* skip = W + off; off += (size_t)8*512*256;
    float* bnsum= W + off; off += (size_t)7*64;       // zeroed together with skip
    float* bufA = W + off; off += (size_t)8*13*32*512;
    float* bufB = W + off; off += (size_t)8*13*32*512;
    float* qe   = W + off; off += (size_t)8*512*16;
    float* ke   = W + off; off += (size_t)8*512*16;
    ushort_t* xbfT = (ushort_t*)(W + off); off += (size_t)8*12*32*512/2;
    ushort_t* qbf  = (ushort_t*)(W + off); off += (size_t)8*12*512*16/2;
    ushort_t* kbf  = (ushort_t*)(W + off); off += (size_t)8*12*512*16/2;
    ushort_t* cwh  = (ushort_t*)(W + off); off += (size_t)32768/2;
    ushort_t* cwl  = (ushort_t*)(W + off); off += (size_t)32768/2;
    ushort_t* qkw  = (ushort_t*)(W + off); off += (size_t)8192/2;
    ushort_t* swbh = (ushort_t*)(W + off); off += (size_t)65536/2;
    ushort_t* swbl = (ushort_t*)(W + off); off += (size_t)65536/2;
    ushort_t* w1ph = (ushort_t*)(W + off); off += (size_t)512*256/2;
    ushort_t* w1pl = (ushort_t*)(W + off); off += (size_t)512*256/2;
    ushort_t* w2ph = (ushort_t*)(W + off); off += (size_t)16*512/2;
    ushort_t* w2pl = (ushort_t*)(W + off); off += (size_t)16*512/2;

    k_prep<<<12226, 256, 0, stream>>>(input, start_w, start_b, gat,
        q_w, q_b, k_w, k_b, filt_w, gate_w, skip_w, end1_w, end2_w,
        skip, qe, ke, bufA,
        cwh, cwl, qkw, swbh, swbl, w1ph, w1pl, w2ph, w2pl);

    const int Tin[8] = {13,12,10,9,7,6,4,3};
    const int Dd[8]  = {1,2,1,2,1,2,1,2};
    float* xin = bufA; float* yb = bufB;
    for (int i = 0; i < 8; i++){
        int Ti = Tin[i], d = Dd[i], To = Ti - d;
        const float* bnsumP = (i == 0) ? bnsum : bnsum + (i-1)*64;
        const float* gP = (i == 0) ? bn_g : bn_g + (i-1)*32;
        const float* bP = (i == 0) ? bn_b : bn_b + (i-1)*32;
        int ident = (i == 0) ? 1 : 0;
        float cnt = 8.0f * (float)Ti * 512.0f;
        k_gated_mfma<<<dim3(4, To, 8), 256, 0, stream>>>(xin, Ti, d, To,
            bnsumP, gP, bP, ident, cnt,
            cwh + i*4096, cwl + i*4096, filt_b + i*32, gate_b + i*32,
            qkw + i*1024, qe + i*8192, ke + i*8192,
            swbh + i*8192, swbl + i*8192, skip_b + i*256,
            skip, xbfT, qbf, kbf, (i < 7) ? 1 : 0);
        if (i < 7){
            k_zpv<<<dim3(4, To, 8), 256, 0, stream>>>(qbf, kbf, xbfT,
                xin, Ti, d, To, bnsumP, gP, bP, ident, cnt,
                gmlp_w + i*2048, gmlp_b + i*32, yb, bnsum + i*64);
            float* tmp = xin; xin = yb; yb = tmp;
        }
    }
    k_end_all<<<dim3(32, 8), 256, 0, stream>>>(skip, w1ph, w1pl, end1_b, w2ph, w2pl, end2_b, out);
}

// Round 13
// 430.280 us; speedup vs baseline: 5.3161x; 1.2313x over previous
//
#include <hip/hip_runtime.h>
#include <math.h>

// Sizes: B=8, IN=2, N=512, T_IN=13, RC=DC=32, SC=256, EC=512, EMB=16, DATT=16, L=8

typedef short v4s __attribute__((ext_vector_type(4)));
typedef float v4f __attribute__((ext_vector_type(4)));
typedef unsigned short ushort_t;

#define MFMA16(a,b,c) __builtin_amdgcn_mfma_f32_16x16x16bf16_1k(a, b, c, 0, 0, 0)

__device__ inline ushort_t f2bf(float f){
    unsigned int u = __builtin_bit_cast(unsigned int, f);
    u += 0x7FFFu + ((u >> 16) & 1u);
    return (ushort_t)(u >> 16);
}
__device__ inline float bf2f(ushort_t h){
    return __builtin_bit_cast(float, ((unsigned int)h) << 16);
}

// One fused prep kernel: zeros (skip+bnsum), qe/ke emb, start pw, all weight splits/permutes.
__global__ void k_prep(
    const float* __restrict__ inp, const float* __restrict__ start_w, const float* __restrict__ start_b,
    const float* __restrict__ gat,
    const float* __restrict__ qw, const float* __restrict__ qb,
    const float* __restrict__ kw, const float* __restrict__ kb,
    const float* __restrict__ filt_w, const float* __restrict__ gate_w,
    const float* __restrict__ skip_w,
    const float* __restrict__ w1, const float* __restrict__ w2,
    float* __restrict__ zero_base,
    float* __restrict__ qe, float* __restrict__ ke, float* __restrict__ x0,
    ushort_t* __restrict__ cwh, ushort_t* __restrict__ cwl, ushort_t* __restrict__ qkw,
    ushort_t* __restrict__ swh, ushort_t* __restrict__ swl,
    ushort_t* __restrict__ w1ph, ushort_t* __restrict__ w1pl,
    ushort_t* __restrict__ w2ph, ushort_t* __restrict__ w2pl)
{
    const int E0 = 1049024;            // skip (1048576) + bnsum (448) zeros
    const int E1 = E0 + 131072;        // emb
    const int E2 = E1 + 1703936;       // start
    const int E3 = E2 + 32768;         // conv w
    const int E4 = E3 + 8192;          // qk w
    const int E5 = E4 + 65536;         // skip w
    const int E6 = E5 + 131072;        // w1 permuted
    const int E7 = E6 + 8192;          // w2 permuted
    int idx = blockIdx.x*256 + threadIdx.x;
    if (idx < E0){
        zero_base[idx] = 0.0f;
    } else if (idx < E1){
        int id = idx - E0;
        const int total = 8*512*16;
        bool isK = id >= total;
        if (isK) id -= total;
        int dq = id & 15; int n = (id >> 4) & 511; int l = id >> 13;
        const float* w = isK ? kw : qw;
        const float* bi = isK ? kb : qb;
        float acc = bi[l*16 + dq];
        const float* wrow = w + (l*16 + dq)*48 + 32;
        #pragma unroll
        for (int e = 0; e < 16; e++) acc += wrow[e] * gat[e*512 + n];
        (isK ? ke : qe)[(l*512 + n)*16 + dq] = isK ? acc : acc*0.25f;
    } else if (idx < E2){
        int id = idx - E1;
        int n = id & 511; int c = (id >> 9) & 31; int r = id >> 14;
        int t = r % 13; int b = r / 13;
        float v0 = inp[((b*2 + 0)*512 + n)*13 + t];
        float v1 = inp[((b*2 + 1)*512 + n)*13 + t];
        x0[id] = start_b[c] + start_w[c*2 + 0]*v0 + start_w[c*2 + 1]*v1;
    } else if (idx < E3){
        int id = idx - E2;
        int k = id & 63, o = (id >> 6) & 63, l = id >> 12;
        int c = k & 31, tap = k >> 5;
        float w = (o < 32) ? filt_w[((l*32 + o)*32 + c)*2 + tap]
                           : gate_w[((l*32 + (o-32))*32 + c)*2 + tap];
        ushort_t hi = f2bf(w);
        cwh[id] = hi; cwl[id] = f2bf(w - bf2f(hi));
    } else if (idx < E4){
        int id = idx - E3;
        int c = id & 31, j = (id >> 5) & 31, l = id >> 10;
        float w = (j < 16) ? qw[(l*16 + j)*48 + c]*0.25f : kw[(l*16 + (j-16))*48 + c];
        qkw[id] = f2bf(w);
    } else if (idx < E5){
        int id = idx - E4;
        float w = skip_w[id];
        ushort_t hi = f2bf(w);
        swh[id] = hi; swl[id] = f2bf(w - bf2f(hi));
    } else if (idx < E6){
        int id = idx - E5;
        int j = id & 15, mm = (id >> 4) & 15, kk = (id >> 8) & 15, ot = id >> 12;
        float w = w1[((size_t)(ot*16 + mm))*256 + kk*16 + j];
        ushort_t hi = f2bf(w);
        w1ph[id] = hi; w1pl[id] = f2bf(w - bf2f(hi));
    } else if (idx < E7){
        int id = idx - E6;
        int j = id & 15, mm = (id >> 4) & 15, kt = id >> 8;
        float w = (mm < 12) ? w2[mm*512 + kt*16 + j] : 0.0f;
        ushort_t hi = f2bf(w);
        w2ph[id] = hi; w2pl[id] = f2bf(w - bf2f(hi));
    }
}

// MFMA gated conv + q/k projection + skip matmul. Block = (nchunk of 128, t, b), 256 thr.
__global__ __launch_bounds__(256) void k_gated_mfma(
    const float* __restrict__ xin, int Tin, int d, int Tout,
    const float* __restrict__ bnsumP, const float* __restrict__ bnG,
    const float* __restrict__ bnB, int ident, float cnt,
    const ushort_t* __restrict__ cwh, const ushort_t* __restrict__ cwl,
    const float* __restrict__ fb, const float* __restrict__ gb,
    const ushort_t* __restrict__ qkw,
    const float* __restrict__ qe, const float* __restrict__ ke,
    const ushort_t* __restrict__ swh, const ushort_t* __restrict__ swl,
    const float* __restrict__ sb,
    float* __restrict__ skip,
    ushort_t* __restrict__ xbfT, ushort_t* __restrict__ qbf, ushort_t* __restrict__ kbf,
    int do_qk)
{
    __shared__ unsigned int XBP[64*129];   // [k 64][n 128+1] packed (hi | lo<<16)
    __shared__ float ABsh[64];
    int tid = threadIdx.x;
    int nch = blockIdx.x, t = blockIdx.y, b = blockIdx.z;
    size_t bt = (size_t)(b*Tout + t);
    int n0 = nch*128;
    int lane = tid & 63, wid = tid >> 6;
    int m16 = lane & 15, g4 = (lane >> 4)*4;

    if (tid < 32){
        float A, Bc;
        if (ident){ A = 1.0f; Bc = 0.0f; }
        else {
            float S = bnsumP[2*tid], S2 = bnsumP[2*tid + 1];
            float m = S/cnt, var = S2/cnt - m*m;
            A = bnG[tid]*rsqrtf(var + 1e-5f);
            Bc = bnB[tid] - m*A;
        }
        ABsh[tid] = A; ABsh[32 + tid] = Bc;
    }
    __syncthreads();

    #pragma unroll
    for (int kk = 0; kk < 16; kk++){
        int k = wid*16 + kk;
        int c = k & 31, tap = k >> 5;
        const float* src = xin + ((size_t)(b*Tin + t + tap*d)*32 + c)*512 + n0 + lane;
        float An = ABsh[c], Bn = ABsh[32 + c];
        #pragma unroll
        for (int h = 0; h < 2; h++){
            float xn = An*src[h*64] + Bn;
            ushort_t hi = f2bf(xn);
            ushort_t lo = f2bf(xn - bf2f(hi));
            XBP[k*129 + h*64 + lane] = (unsigned int)hi | ((unsigned int)lo << 16);
        }
    }
    v4s ah[4][4], al[4][4];
    #pragma unroll
    for (int ot = 0; ot < 4; ot++)
    #pragma unroll
    for (int kt = 0; kt < 4; kt++){
        ah[ot][kt] = *(const v4s*)(cwh + (ot*16 + m16)*64 + kt*16 + g4);
        al[ot][kt] = *(const v4s*)(cwl + (ot*16 + m16)*64 + kt*16 + g4);
    }
    v4f acc[4][2];
    #pragma unroll
    for (int ot = 0; ot < 4; ot++){
        float4 bv = *(const float4*)((ot < 2 ? fb + ot*16 : gb + (ot-2)*16) + g4);
        acc[ot][0] = (v4f){bv.x, bv.y, bv.z, bv.w};
        acc[ot][1] = (v4f){bv.x, bv.y, bv.z, bv.w};
    }
    __syncthreads();
    v4s bh[2][4], bl[2][4];
    #pragma unroll
    for (int nt = 0; nt < 2; nt++){
        int nl = (wid*2 + nt)*16 + m16;
        #pragma unroll
        for (int kt = 0; kt < 4; kt++){
            unsigned int u0 = XBP[(kt*16 + g4 + 0)*129 + nl];
            unsigned int u1 = XBP[(kt*16 + g4 + 1)*129 + nl];
            unsigned int u2 = XBP[(kt*16 + g4 + 2)*129 + nl];
            unsigned int u3 = XBP[(kt*16 + g4 + 3)*129 + nl];
            v4s hh, ll;
            hh[0] = (short)(u0 & 0xffffu); ll[0] = (short)(u0 >> 16);
            hh[1] = (short)(u1 & 0xffffu); ll[1] = (short)(u1 >> 16);
            hh[2] = (short)(u2 & 0xffffu); ll[2] = (short)(u2 >> 16);
            hh[3] = (short)(u3 & 0xffffu); ll[3] = (short)(u3 >> 16);
            bh[nt][kt] = hh; bl[nt][kt] = ll;
        }
    }
    #pragma unroll
    for (int kt = 0; kt < 4; kt++)
    #pragma unroll
    for (int ot = 0; ot < 4; ot++)
    #pragma unroll
    for (int nt = 0; nt < 2; nt++){
        acc[ot][nt] = MFMA16(ah[ot][kt], bh[nt][kt], acc[ot][nt]);
        acc[ot][nt] = MFMA16(ah[ot][kt], bl[nt][kt], acc[ot][nt]);
        acc[ot][nt] = MFMA16(al[ot][kt], bh[nt][kt], acc[ot][nt]);
    }
    v4s xh[2][2], xl[2][2];
    #pragma unroll
    for (int ct = 0; ct < 2; ct++)
    #pragma unroll
    for (int nt = 0; nt < 2; nt++){
        v4s hh, ll;
        #pragma unroll
        for (int i = 0; i < 4; i++){
            float f = acc[ct][nt][i], g = acc[ct+2][nt][i];
            float e2 = __expf(2.0f*f);
            float th = 1.0f - 2.0f/(e2 + 1.0f);
            float sg = 1.0f/(1.0f + __expf(-g));
            float v = th*sg;
            ushort_t hi = f2bf(v);
            hh[i] = (short)hi; ll[i] = (short)f2bf(v - bf2f(hi));
        }
        xh[ct][nt] = hh; xl[ct][nt] = ll;
    }
    if (do_qk){
        #pragma unroll
        for (int ct = 0; ct < 2; ct++)
        #pragma unroll
        for (int nt = 0; nt < 2; nt++){
            int nl = n0 + (wid*2 + nt)*16 + m16;
            #pragma unroll
            for (int i = 0; i < 4; i++)
                xbfT[(bt*32 + ct*16 + g4 + i)*512 + nl] = (ushort_t)xh[ct][nt][i];
        }
        v4s qa[2][2];
        #pragma unroll
        for (int ot = 0; ot < 2; ot++)
        #pragma unroll
        for (int kt = 0; kt < 2; kt++)
            qa[ot][kt] = *(const v4s*)(qkw + (ot*16 + m16)*32 + kt*16 + g4);
        #pragma unroll
        for (int ot = 0; ot < 2; ot++)
        #pragma unroll
        for (int nt = 0; nt < 2; nt++){
            int nl = n0 + (wid*2 + nt)*16 + m16;
            float4 ev = *(const float4*)((ot == 0 ? qe : ke) + nl*16 + g4);
            v4f a2 = (v4f){ev.x, ev.y, ev.z, ev.w};
            #pragma unroll
            for (int kt = 0; kt < 2; kt++)
                a2 = MFMA16(qa[ot][kt], xh[kt][nt], a2);
            v4s r;
            #pragma unroll
            for (int i = 0; i < 4; i++) r[i] = (short)f2bf(a2[i]);
            *(v4s*)((ot == 0 ? qbf : kbf) + (bt*512 + nl)*16 + g4) = r;
        }
    }
    if (t == Tout - 1){
        #pragma unroll 4
        for (int ot = 0; ot < 16; ot++){
            v4s sh_[2], sl_[2];
            #pragma unroll
            for (int kt = 0; kt < 2; kt++){
                sh_[kt] = *(const v4s*)(swh + (ot*16 + m16)*32 + kt*16 + g4);
                sl_[kt] = *(const v4s*)(swl + (ot*16 + m16)*32 + kt*16 + g4);
            }
            float4 sbv = *(const float4*)(sb + ot*16 + g4);
            #pragma unroll
            for (int nt = 0; nt < 2; nt++){
                int nl = n0 + (wid*2 + nt)*16 + m16;
                float* sp = skip + ((size_t)(b*512) + nl)*256 + ot*16 + g4;
                float4 old = *(const float4*)sp;
                v4f a3 = (v4f){old.x + sbv.x, old.y + sbv.y, old.z + sbv.z, old.w + sbv.w};
                #pragma unroll
                for (int kt = 0; kt < 2; kt++){
                    a3 = MFMA16(sh_[kt], xh[kt][nt], a3);
                    a3 = MFMA16(sh_[kt], xl[kt][nt], a3);
                    a3 = MFMA16(sl_[kt], xh[kt][nt], a3);
                }
                *(float4*)sp = make_float4(a3[0], a3[1], a3[2], a3[3]);
            }
        }
    }
}

// Z pass: rz[v] = 1/sum_w exp(q_v . k_w). Block = (vchunk of 128, bt). 256 thr, 2 v-tiles/wave.
__global__ __launch_bounds__(256) void k_z(
    const ushort_t* __restrict__ qbf, const ushort_t* __restrict__ kbf,
    int Tout, float* __restrict__ rz)
{
    __shared__ ushort_t KS[512*20];
    int tid = threadIdx.x;
    int vchunk = blockIdx.x, t = blockIdx.y, b = blockIdx.z;
    size_t bt = (size_t)(b*Tout + t);
    const ushort_t* kg = kbf + bt*8192;
    const ushort_t* qg = qbf + bt*8192;
    {
        const uint2* s0 = (const uint2*)(kg + tid*16);
        uint2* d0 = (uint2*)(KS + tid*20);
        d0[0]=s0[0]; d0[1]=s0[1]; d0[2]=s0[2]; d0[3]=s0[3];
        const uint2* s1 = (const uint2*)(kg + (tid+256)*16);
        uint2* d1 = (uint2*)(KS + (tid+256)*20);
        d1[0]=s1[0]; d1[1]=s1[1]; d1[2]=s1[2]; d1[3]=s1[3];
    }
    int l = tid & 63, wid = tid >> 6;
    int m16 = l & 15, g4 = (l >> 4)*4;
    __syncthreads();
    #pragma unroll
    for (int vi = 0; vi < 2; vi++){
        int vt = vchunk*8 + wid*2 + vi;
        v4s bq = *(const v4s*)(qg + (vt*16 + m16)*16 + g4);
        float zp = 0.f;
        for (int wt = 0; wt < 32; wt++){
            v4s ak = *(const v4s*)(KS + (wt*16 + m16)*20 + g4);
            v4f s = MFMA16(ak, bq, ((v4f){0.f,0.f,0.f,0.f}));
            zp += __expf(fminf(s[0],60.f)) + __expf(fminf(s[1],60.f))
                + __expf(fminf(s[2],60.f)) + __expf(fminf(s[3],60.f));
        }
        zp += __shfl_xor(zp, 16);
        zp += __shfl_xor(zp, 32);
        if (l < 16) rz[bt*512 + vt*16 + l] = 1.0f/zp;
    }
}

// PV + gmlp + residual + BN atomic partials. Block = (wchunk of 128, bt). 256 thr, 2 w-tiles/wave.
__global__ __launch_bounds__(256) void k_pv(
    const ushort_t* __restrict__ qbf, const ushort_t* __restrict__ kbf,
    const ushort_t* __restrict__ xbfT, const float* __restrict__ rz,
    const float* __restrict__ xin, int Tin, int d, int Tout,
    const float* __restrict__ bnsumP, const float* __restrict__ bnG,
    const float* __restrict__ bnB, int ident, float cnt,
    const float* __restrict__ gw, const float* __restrict__ gb,
    float* __restrict__ y, float* __restrict__ bnsumOut)
{
    __shared__ ushort_t QS[512*20];
    __shared__ ushort_t XT[32*520];
    __shared__ float rzs[512];
    __shared__ float bnsh[256];
    __shared__ float ABsh[64];
    int tid = threadIdx.x;
    int wc = blockIdx.x, t = blockIdx.y, b = blockIdx.z;
    size_t bt = (size_t)(b*Tout + t);
    const ushort_t* qg = qbf + bt*8192;
    const ushort_t* kg = kbf + bt*8192;
    {
        const uint2* s0 = (const uint2*)(qg + tid*16);
        uint2* d0 = (uint2*)(QS + tid*20);
        d0[0]=s0[0]; d0[1]=s0[1]; d0[2]=s0[2]; d0[3]=s0[3];
        const uint2* s1 = (const uint2*)(qg + (tid+256)*16);
        uint2* d1 = (uint2*)(QS + (tid+256)*20);
        d1[0]=s1[0]; d1[1]=s1[1]; d1[2]=s1[2]; d1[3]=s1[3];
        int c = tid >> 3, seg = tid & 7;
        const uint4* xs = (const uint4*)(xbfT + bt*16384 + c*512 + seg*64);
        uint4* xd = (uint4*)(XT + c*520 + seg*64);
        #pragma unroll
        for (int j = 0; j < 8; j++) xd[j] = xs[j];
        rzs[tid] = rz[bt*512 + tid];
        rzs[tid + 256] = rz[bt*512 + tid + 256];
    }
    if (tid < 32){
        float A, Bc;
        if (ident){ A = 1.0f; Bc = 0.0f; }
        else {
            float S = bnsumP[2*tid], S2 = bnsumP[2*tid + 1];
            float m = S/cnt, var = S2/cnt - m*m;
            A = bnG[tid]*rsqrtf(var + 1e-5f);
            Bc = bnB[tid] - m*A;
        }
        ABsh[tid] = A; ABsh[32 + tid] = Bc;
    }
    int l = tid & 63, wid = tid >> 6;
    int m16 = l & 15, g4 = (l >> 4)*4;
    v4s AG[2][2][2];
    #pragma unroll
    for (int pt = 0; pt < 2; pt++)
    #pragma unroll
    for (int ot = 0; ot < 2; ot++)
    #pragma unroll
    for (int ct = 0; ct < 2; ct++){
        float4 gv = *(const float4*)(gw + (ot*16 + m16)*64 + pt*32 + ct*16 + g4);
        v4s r; r[0] = (short)f2bf(gv.x); r[1] = (short)f2bf(gv.y);
        r[2] = (short)f2bf(gv.z); r[3] = (short)f2bf(gv.w);
        AG[pt][ot][ct] = r;
    }
    v4f gbv[2];
    #pragma unroll
    for (int ot = 0; ot < 2; ot++) gbv[ot] = *(const v4f*)(gb + ot*16 + g4);
    int wt0 = wc*8 + wid*2;
    v4s bk[2];
    bk[0] = *(const v4s*)(kg + (wt0*16 + m16)*16 + g4);
    bk[1] = *(const v4s*)(kg + ((wt0+1)*16 + m16)*16 + g4);
    __syncthreads();
    v4f An[2], Bn[2];
    #pragma unroll
    for (int ot = 0; ot < 2; ot++){
        #pragma unroll
        for (int i = 0; i < 4; i++){
            An[ot][i] = ABsh[ot*16 + g4 + i];
            Bn[ot][i] = ABsh[32 + ot*16 + g4 + i];
        }
    }
    v4f c2[2][2];
    #pragma unroll
    for (int i = 0; i < 2; i++){ c2[i][0] = (v4f){0.f,0.f,0.f,0.f}; c2[i][1] = (v4f){0.f,0.f,0.f,0.f}; }
    for (int vt = 0; vt < 32; vt++){
        v4s aq = *(const v4s*)(QS + (vt*16 + m16)*20 + g4);
        v4f s0 = MFMA16(aq, bk[0], ((v4f){0.f,0.f,0.f,0.f}));
        v4f s1 = MFMA16(aq, bk[1], ((v4f){0.f,0.f,0.f,0.f}));
        v4f rzv = *(const v4f*)(rzs + vt*16 + g4);
        v4s p0, p1;
        #pragma unroll
        for (int i = 0; i < 4; i++){
            p0[i] = (short)f2bf(__expf(fminf(s0[i],60.f)) * rzv[i]);
            p1[i] = (short)f2bf(__expf(fminf(s1[i],60.f)) * rzv[i]);
        }
        #pragma unroll
        for (int ct = 0; ct < 2; ct++){
            v4s ax = *(const v4s*)(XT + (ct*16 + m16)*520 + vt*16 + g4);
            c2[0][ct] = MFMA16(ax, p0, c2[0][ct]);
            c2[1][ct] = MFMA16(ax, p1, c2[1][ct]);
        }
    }
    float bs1[2][4], bs2[2][4];
    #pragma unroll
    for (int ot = 0; ot < 2; ot++)
    #pragma unroll
    for (int i = 0; i < 4; i++){ bs1[ot][i] = 0.f; bs2[ot][i] = 0.f; }
    #pragma unroll
    for (int wtl = 0; wtl < 2; wtl++){
        int wt = wt0 + wtl;
        v4s bxa[2], bx[2];
        #pragma unroll
        for (int ct = 0; ct < 2; ct++){
            v4s r;
            #pragma unroll
            for (int i = 0; i < 4; i++) r[i] = (short)f2bf(c2[wtl][ct][i]);
            bxa[ct] = r;
            v4s q;
            #pragma unroll
            for (int i = 0; i < 4; i++) q[i] = (short)XT[(ct*16 + g4 + i)*520 + wt*16 + m16];
            bx[ct] = q;
        }
        v4f c3[2];
        #pragma unroll
        for (int ot = 0; ot < 2; ot++){
            c3[ot] = gbv[ot];
            #pragma unroll
            for (int ct = 0; ct < 2; ct++){
                c3[ot] = MFMA16(AG[1][ot][ct], bxa[ct], c3[ot]);
                c3[ot] = MFMA16(AG[0][ot][ct], bx[ct],  c3[ot]);
            }
        }
        int wg = wt*16 + m16;
        const float* resbase = xin + ((size_t)(b*Tin + t + d)*32)*512 + wg;
        float* ybase = y + (bt*32)*512 + wg;
        #pragma unroll
        for (int ot = 0; ot < 2; ot++){
            #pragma unroll
            for (int i = 0; i < 4; i++){
                int outc = ot*16 + g4 + i;
                float yv = c3[ot][i] + An[ot][i]*resbase[(size_t)outc*512] + Bn[ot][i];
                ybase[(size_t)outc*512] = yv;
                bs1[ot][i] += yv; bs2[ot][i] += yv*yv;
            }
        }
    }
    #pragma unroll
    for (int off = 1; off <= 8; off <<= 1){
        #pragma unroll
        for (int ot = 0; ot < 2; ot++)
        #pragma unroll
        for (int i = 0; i < 4; i++){
            bs1[ot][i] += __shfl_xor(bs1[ot][i], off);
            bs2[ot][i] += __shfl_xor(bs2[ot][i], off);
        }
    }
    if (m16 == 0){
        #pragma unroll
        for (int ot = 0; ot < 2; ot++)
        #pragma unroll
        for (int i = 0; i < 4; i++){
            int c = ot*16 + g4 + i;
            bnsh[(wid*32 + c)*2 + 0] = bs1[ot][i];
            bnsh[(wid*32 + c)*2 + 1] = bs2[ot][i];
        }
    }
    __syncthreads();
    if (tid < 64){
        int c = tid & 31, pp = tid >> 5;
        float s = 0.f;
        #pragma unroll
        for (int w = 0; w < 4; w++) s += bnsh[(w*32 + c)*2 + pp];
        atomicAdd(&bnsumOut[c*2 + pp], s);
    }
}

// Fused end: relu(skip)->split->GEMM1(MFMA, permuted w1)->relu->GEMM2(all waves)->out.
__global__ __launch_bounds__(256) void k_end_all(
    const float* __restrict__ skip,
    const ushort_t* __restrict__ w1ph, const ushort_t* __restrict__ w1pl,
    const float* __restrict__ b1,
    const ushort_t* __restrict__ w2ph, const ushort_t* __restrict__ w2pl,
    const float* __restrict__ b2, float* __restrict__ out)
{
    __shared__ ushort_t SH[16*264], SL[16*264];
    __shared__ ushort_t HH[512*18], HL[512*18];
    __shared__ float PS[4][16][17];
    int tid = threadIdx.x;
    int nc = blockIdx.x, b = blockIdx.y;
    int n0 = nc*16;
    {
        int n = tid >> 4, s = tid & 15;
        const float4* src = (const float4*)(skip + ((size_t)(b*512 + n0 + n))*256 + s*16);
        #pragma unroll
        for (int j = 0; j < 4; j++){
            float4 v4_ = src[j];
            float vv[4] = {v4_.x, v4_.y, v4_.z, v4_.w};
            #pragma unroll
            for (int e = 0; e < 4; e++){
                float v = fmaxf(vv[e], 0.f);
                ushort_t h = f2bf(v);
                SH[n*264 + s*16 + j*4 + e] = h;
                SL[n*264 + s*16 + j*4 + e] = f2bf(v - bf2f(h));
            }
        }
    }
    __syncthreads();
    int l = tid & 63, wid = tid >> 6;
    int m16 = l & 15, g4 = (l >> 4)*4;
    v4f acc[8];
    #pragma unroll
    for (int nt = 0; nt < 8; nt++){
        float bo = b1[(wid*8 + nt)*16 + m16];
        acc[nt] = (v4f){bo, bo, bo, bo};
    }
    for (int kk = 0; kk < 16; kk++){
        v4s ahi = *(const v4s*)(SH + m16*264 + kk*16 + g4);
        v4s alo = *(const v4s*)(SL + m16*264 + kk*16 + g4);
        #pragma unroll
        for (int nt = 0; nt < 8; nt++){
            int ob = ((wid*8 + nt)*16 + kk)*256;
            v4s bhi = *(const v4s*)(w1ph + ob + m16*16 + g4);
            v4s blo = *(const v4s*)(w1pl + ob + m16*16 + g4);
            acc[nt] = MFMA16(ahi, bhi, acc[nt]);
            acc[nt] = MFMA16(ahi, blo, acc[nt]);
            acc[nt] = MFMA16(alo, bhi, acc[nt]);
        }
    }
    #pragma unroll
    for (int nt = 0; nt < 8; nt++){
        int o = (wid*8 + nt)*16 + m16;
        #pragma unroll
        for (int i = 0; i < 4; i++){
            float v = fmaxf(acc[nt][i], 0.f);
            ushort_t h = f2bf(v);
            HH[o*18 + g4 + i] = h;
            HL[o*18 + g4 + i] = f2bf(v - bf2f(h));
        }
    }
    __syncthreads();
    v4f a4 = (v4f){0.f, 0.f, 0.f, 0.f};
    for (int q = 0; q < 8; q++){
        int kt = wid*8 + q;
        v4s wh = *(const v4s*)(w2ph + kt*256 + m16*16 + g4);
        v4s wl = *(const v4s*)(w2pl + kt*256 + m16*16 + g4);
        v4s hh, hl;
        #pragma unroll
        for (int i = 0; i < 4; i++){
            int k = kt*16 + g4 + i;
            hh[i] = (short)HH[k*18 + m16];
            hl[i] = (short)HL[k*18 + m16];
        }
        a4 = MFMA16(wh, hh, a4);
        a4 = MFMA16(wh, hl, a4);
        a4 = MFMA16(wl, hh, a4);
    }
    #pragma unroll
    for (int i = 0; i < 4; i++) PS[wid][g4 + i][m16] = a4[i];
    __syncthreads();
    if (wid == 0){
        #pragma unroll
        for (int i = 0; i < 4; i++){
            int od = g4 + i;
            if (od < 12){
                float v = b2[od] + PS[0][od][m16] + PS[1][od][m16]
                        + PS[2][od][m16] + PS[3][od][m16];
                out[((size_t)(b*12 + od))*512 + n0 + m16] = v;
            }
        }
    }
}

extern "C" void kernel_launch(void* const* d_in, const int* in_sizes, int n_in,
                              void* d_out, int out_size, void* d_ws, size_t ws_size,
                              hipStream_t stream)
{
    (void)in_sizes; (void)n_in; (void)out_size; (void)ws_size;
    const float* input  = (const float*)d_in[0];
    const float* gat    = (const float*)d_in[1];
    const float* start_w= (const float*)d_in[2];
    const float* start_b= (const float*)d_in[3];
    const float* filt_w = (const float*)d_in[4];
    const float* filt_b = (const float*)d_in[5];
    const float* gate_w = (const float*)d_in[6];
    const float* gate_b = (const float*)d_in[7];
    const float* skip_w = (const float*)d_in[8];
    const float* skip_b = (const float*)d_in[9];
    const float* q_w    = (const float*)d_in[10];
    const float* q_b    = (const float*)d_in[11];
    const float* k_w    = (const float*)d_in[12];
    const float* k_b    = (const float*)d_in[13];
    const float* gmlp_w = (const float*)d_in[14];
    const float* gmlp_b = (const float*)d_in[15];
    const float* bn_g   = (const float*)d_in[16];
    const float* bn_b   = (const float*)d_in[17];
    const float* end1_w = (const float*)d_in[18];
    const float* end1_b = (const float*)d_in[19];
    const float* end2_w = (const float*)d_in[20];
    const float* end2_b = (const float*)d_in[21];
    float* out = (float*)d_out;

    float* W = (float*)d_ws;
    size_t off = 0;
    float* skip = W + off; off += (size_t)8*512*256;
    float* bnsum= W + off; off += (size_t)7*64;       // zeroed together with skip
    float* bufA = W + off; off += (size_t)8*13*32*512;
    float* bufB = W + off; off += (size_t)8*13*32*512;
    float* qe   = W + off; off += (size_t)8*512*16;
    float* ke   = W + off; off += (size_t)8*512*16;
    float* rz   = W + off; off += (size_t)8*12*512;
    ushort_t* xbfT = (ushort_t*)(W + off); off += (size_t)8*12*32*512/2;
    ushort_t* qbf  = (ushort_t*)(W + off); off += (size_t)8*12*512*16/2;
    ushort_t* kbf  = (ushort_t*)(W + off); off += (size_t)8*12*512*16/2;
    ushort_t* cwh  = (ushort_t*)(W + off); off += (size_t)32768/2;
    ushort_t* cwl  = (ushort_t*)(W + off); off += (size_t)32768/2;
    ushort_t* qkw  = (ushort_t*)(W + off); off += (size_t)8192/2;
    ushort_t* swbh = (ushort_t*)(W + off); off += (size_t)65536/2;
    ushort_t* swbl = (ushort_t*)(W + off); off += (size_t)65536/2;
    ushort_t* w1ph = (ushort_t*)(W + off); off += (size_t)512*256/2;
    ushort_t* w1pl = (ushort_t*)(W + off); off += (size_t)512*256/2;
    ushort_t* w2ph = (ushort_t*)(W + off); off += (size_t)16*512/2;
    ushort_t* w2pl = (ushort_t*)(W + off); off += (size_t)16*512/2;

    k_prep<<<12226, 256, 0, stream>>>(input, start_w, start_b, gat,
        q_w, q_b, k_w, k_b, filt_w, gate_w, skip_w, end1_w, end2_w,
        skip, qe, ke, bufA,
        cwh, cwl, qkw, swbh, swbl, w1ph, w1pl, w2ph, w2pl);

    const int Tin[8] = {13,12,10,9,7,6,4,3};
    const int Dd[8]  = {1,2,1,2,1,2,1,2};
    float* xin = bufA; float* yb = bufB;
    for (int i = 0; i < 8; i++){
        int Ti = Tin[i], d = Dd[i], To = Ti - d;
        const float* bnsumP = (i == 0) ? bnsum : bnsum + (i-1)*64;
        const float* gP = (i == 0) ? bn_g : bn_g + (i-1)*32;
        const float* bP = (i == 0) ? bn_b : bn_b + (i-1)*32;
        int ident = (i == 0) ? 1 : 0;
        float cnt = 8.0f * (float)Ti * 512.0f;
        k_gated_mfma<<<dim3(4, To, 8), 256, 0, stream>>>(xin, Ti, d, To,
            bnsumP, gP, bP, ident, cnt,
            cwh + i*4096, cwl + i*4096, filt_b + i*32, gate_b + i*32,
            qkw + i*1024, qe + i*8192, ke + i*8192,
            swbh + i*8192, swbl + i*8192, skip_b + i*256,
            skip, xbfT, qbf, kbf, (i < 7) ? 1 : 0);
        if (i < 7){
            k_z<<<dim3(4, To, 8), 256, 0, stream>>>(qbf, kbf, To, rz);
            k_pv<<<dim3(4, To, 8), 256, 0, stream>>>(qbf, kbf, xbfT, rz,
                xin, Ti, d, To, bnsumP, gP, bP, ident, cnt,
                gmlp_w + i*2048, gmlp_b + i*32, yb, bnsum + i*64);
            float* tmp = xin; xin = yb; yb = tmp;
        }
    }
    k_end_all<<<dim3(32, 8), 256, 0, stream>>>(skip, w1ph, w1pl, end1_b, w2ph, w2pl, end2_b, out);
}